// Round 1
// baseline (644.097 us; speedup 1.0000x reference)
//
#include <hip/hip_runtime.h>
#include <cstddef>

#define B_   2
#define T_   4096
#define D_   1024
#define H_   16
#define KD_  512
#define VD_  1024
#define HK_  32
#define HV_  64
#define CH_  64
#define NC_  64          // T/CHUNK
#define M_   (B_*T_)     // 8192
#define GR_  16
#define EPS_ 1e-5f
#define SCALE_ 0.17677669529663687f  // 32^-0.5
#define GNORM_INV_ (1.0f/16.0f)

typedef __bf16 bf16_t;
typedef __attribute__((ext_vector_type(8))) __bf16 bf16x8;
typedef __attribute__((ext_vector_type(4))) float f32x4;

__device__ inline unsigned short f2bf(float f) {
  unsigned int u = __float_as_uint(f);
  u = (u + 0x7fffu + ((u >> 16) & 1u)) >> 16;
  return (unsigned short)u;
}

// ---------------- elementwise conversions ----------------

__global__ __launch_bounds__(256) void k_f32_to_bf16(const float* __restrict__ in,
                                                     unsigned short* __restrict__ out, int n4) {
  int i = (blockIdx.x * 256 + threadIdx.x) * 4;
  float4 f = *(const float4*)(in + i);
  ushort4 o;
  o.x = f2bf(f.x); o.y = f2bf(f.y); o.z = f2bf(f.z); o.w = f2bf(f.w);
  *(ushort4*)(out + i) = o;
}

// in: K x N f32 row-major; out: N x K bf16 row-major
__global__ __launch_bounds__(256) void k_transpose_bf16(const float* __restrict__ in,
                                                        unsigned short* __restrict__ out,
                                                        int K, int N) {
  __shared__ float tile[32][33];
  int n0 = blockIdx.x * 32, k0 = blockIdx.y * 32;
  int tx = threadIdx.x & 31, ty = threadIdx.x >> 5;   // 32 x 8
#pragma unroll
  for (int p = 0; p < 4; ++p)
    tile[ty + p*8][tx] = in[(size_t)(k0 + ty + p*8) * N + n0 + tx];
  __syncthreads();
#pragma unroll
  for (int p = 0; p < 4; ++p)
    out[(size_t)(n0 + ty + p*8) * K + k0 + tx] = f2bf(tile[tx][ty + p*8]);
}

// Wgk1: D x GR f32 -> padded transposed 128 x D bf16 (rows >= GR are zero)
__global__ __launch_bounds__(256) void k_pad_wgk1(const float* __restrict__ w,
                                                  unsigned short* __restrict__ out) {
  int idx = blockIdx.x * 256 + threadIdx.x;     // 128 * 1024
  int n = idx >> 10, kk = idx & 1023;
  float v = (n < GR_) ? w[kk * GR_ + n] : 0.0f;
  out[idx] = f2bf(v);
}

// ---------------- bf16 MFMA GEMM: C(MxN,f32) = A(MxK,bf16 rowmajor) * Bt(NxK,bf16 rowmajor)^T ----------------
// 128x128 tile, BK=64, 256 threads (4 waves, 2x2), 16x16x32 MFMA, XOR-swizzled LDS.

__global__ __launch_bounds__(256) void k_gemm_bt(const unsigned short* __restrict__ A,
                                                 const unsigned short* __restrict__ Bt,
                                                 float* __restrict__ C,
                                                 int M, int N, int K) {
  __shared__ __align__(16) unsigned short sA[128 * 64];
  __shared__ __align__(16) unsigned short sB[128 * 64];
  const int tid  = threadIdx.x;
  const int lane = tid & 63;
  const int wave = tid >> 6;
  const int wr = wave >> 1, wc = wave & 1;
  const int quad = lane >> 4, l16 = lane & 15;
  const int bm0 = blockIdx.y * 128, bn0 = blockIdx.x * 128;
  const int srow = tid >> 3;            // 0..31
  const int sg   = tid & 7;             // k-group 0..7 (8 elems each)

  f32x4 acc[4][4] = {};

  for (int k0 = 0; k0 < K; k0 += 64) {
    uint4 ra[4], rb[4];
#pragma unroll
    for (int p = 0; p < 4; ++p) {
      int r = srow + p * 32;
      ra[p] = *(const uint4*)(A  + (size_t)(bm0 + r) * K + k0 + sg * 8);
      rb[p] = *(const uint4*)(Bt + (size_t)(bn0 + r) * K + k0 + sg * 8);
    }
    __syncthreads();
#pragma unroll
    for (int p = 0; p < 4; ++p) {
      int r = srow + p * 32;
      int g = sg ^ (r & 7);
      *(uint4*)(sA + r * 64 + g * 8) = ra[p];
      *(uint4*)(sB + r * 64 + g * 8) = rb[p];
    }
    __syncthreads();
#pragma unroll
    for (int kk = 0; kk < 2; ++kk) {
      bf16x8 af[4], bfv[4];
#pragma unroll
      for (int i = 0; i < 4; ++i) {
        int row = wr * 64 + i * 16 + l16;
        int g = (kk * 4 + quad) ^ (row & 7);
        af[i] = *(const bf16x8*)(sA + row * 64 + g * 8);
      }
#pragma unroll
      for (int j = 0; j < 4; ++j) {
        int row = wc * 64 + j * 16 + l16;
        int g = (kk * 4 + quad) ^ (row & 7);
        bfv[j] = *(const bf16x8*)(sB + row * 64 + g * 8);
      }
#pragma unroll
      for (int i = 0; i < 4; ++i)
#pragma unroll
        for (int j = 0; j < 4; ++j)
          acc[i][j] = __builtin_amdgcn_mfma_f32_16x16x32_bf16(af[i], bfv[j], acc[i][j], 0, 0, 0);
    }
  }

#pragma unroll
  for (int i = 0; i < 4; ++i) {
    int row0 = bm0 + wr * 64 + i * 16 + quad * 4;
#pragma unroll
    for (int j = 0; j < 4; ++j) {
      int col = bn0 + wc * 64 + j * 16 + l16;
#pragma unroll
      for (int r = 0; r < 4; ++r)
        C[(size_t)(row0 + r) * N + col] = acc[i][j][r];
    }
  }
}

// ---------------- gate: gk = log_sigmoid(glow @ Wgk2 + bgk) / 16 ----------------

__global__ __launch_bounds__(256) void k_gate(const float* __restrict__ glow,
                                              const float* __restrict__ Wgk2,
                                              const float* __restrict__ bgk,
                                              float* __restrict__ gk) {
  int idx = blockIdx.x * 256 + threadIdx.x;   // M * KD
  int t = idx >> 9, n = idx & 511;
  const float* gr = glow + (size_t)t * 128;
  float s = bgk[n];
#pragma unroll
  for (int r = 0; r < GR_; ++r) s += gr[r] * Wgk2[r * KD_ + n];
  float ls = fminf(s, 0.0f) - log1pf(expf(-fabsf(s)));
  gk[idx] = ls * GNORM_INV_;
}

// ---------------- attention phase 1: per chunk-head intra work ----------------
// qbuf: in q -> out qe (in place). vo: in v -> out o_intra (in place).
// U[(c*32+bh)*2048 + d*64 + vd], dvec[(c*32+bh)*32 + d] = exp(b_last)

__global__ __launch_bounds__(256) void k_phase1(float* __restrict__ qbuf,
                                                const float* __restrict__ kbuf,
                                                const float* __restrict__ gkbuf,
                                                float* __restrict__ vo,
                                                float* __restrict__ U,
                                                float* __restrict__ dvec) {
  const int bi = blockIdx.x;
  const int c = bi >> 5, bh = bi & 31;
  const int b = bh >> 4, h = bh & 15;
  const int tid = threadIdx.x;

  __shared__ float sq[64 * 32];
  __shared__ float sk[64 * 32];
  __shared__ float sb[64 * 32];
  __shared__ float sv[64 * 64];
  __shared__ float sA[64 * 65];
  __shared__ float ebl[32];

  const size_t rq = (size_t)(b * T_ + c * 64) * KD_ + h * 32;
  const size_t rv = (size_t)(b * T_ + c * 64) * VD_ + h * 64;

#pragma unroll
  for (int s = 0; s < 8; ++s) {
    int e = tid + s * 256;
    int i = e >> 5, d = e & 31;
    size_t go = rq + (size_t)i * KD_ + d;
    sq[e] = qbuf[go];
    sk[e] = kbuf[go];
    sb[e] = gkbuf[go];
  }
#pragma unroll
  for (int s = 0; s < 16; ++s) {
    int e = tid + s * 256;
    int i = e >> 6, vd = e & 63;
    sv[e] = vo[rv + (size_t)i * VD_ + vd];
  }
  __syncthreads();

  if (tid < 32) {
    float run = 0.0f;
    for (int i = 0; i < 64; ++i) { run += sb[i * 32 + tid]; sb[i * 32 + tid] = run; }
    float e = expf(run);
    ebl[tid] = e;
    dvec[((size_t)c * 32 + bh) * 32 + tid] = e;
  }
  __syncthreads();

#pragma unroll
  for (int s = 0; s < 8; ++s) {
    int e = tid + s * 256;
    int i = e >> 5, d = e & 31;
    float bb = sb[e];
    float qe = sq[e] * expf(bb) * SCALE_;
    sq[e] = qe;
    qbuf[rq + (size_t)i * KD_ + d] = qe;
    sk[e] = sk[e] * expf(-bb);   // ke2
  }
  __syncthreads();

  // A = qe @ ke2^T, masked lower-tri.  4x4 tiles, 16x16 tile grid.
  {
    int ti = tid >> 4, tj = tid & 15;
    int i0 = ti * 4, j0 = tj * 4;
    float a[4][4] = {};
    if (j0 <= i0 + 3) {
      for (int dd = 0; dd < 32; ++dd) {
        int d = (dd + tid) & 31;   // stagger: avoid same-bank across lanes
        float qv[4], kv[4];
#pragma unroll
        for (int x = 0; x < 4; ++x) qv[x] = sq[(i0 + x) * 32 + d];
#pragma unroll
        for (int y = 0; y < 4; ++y) kv[y] = sk[(j0 + y) * 32 + d];
#pragma unroll
        for (int x = 0; x < 4; ++x)
#pragma unroll
          for (int y = 0; y < 4; ++y) a[x][y] += qv[x] * kv[y];
      }
    }
#pragma unroll
    for (int x = 0; x < 4; ++x)
#pragma unroll
      for (int y = 0; y < 4; ++y)
        sA[(i0 + x) * 65 + j0 + y] = (j0 + y <= i0 + x) ? a[x][y] : 0.0f;
  }
  __syncthreads();

  // o_intra = A @ v   (writes o over v region)
  {
    int ti = tid >> 4, tv = tid & 15;
    int i0 = ti * 4, v0 = tv * 4;
    float o[4][4] = {};
    int jmax = i0 + 3;
    for (int j = 0; j <= jmax; ++j) {
      float av[4], vv[4];
#pragma unroll
      for (int x = 0; x < 4; ++x) av[x] = sA[(i0 + x) * 65 + j];
#pragma unroll
      for (int y = 0; y < 4; ++y) vv[y] = sv[j * 64 + v0 + y];
#pragma unroll
      for (int x = 0; x < 4; ++x)
#pragma unroll
        for (int y = 0; y < 4; ++y) o[x][y] += av[x] * vv[y];
    }
#pragma unroll
    for (int x = 0; x < 4; ++x)
#pragma unroll
      for (int y = 0; y < 4; ++y)
        vo[rv + (size_t)(i0 + x) * VD_ + v0 + y] = o[x][y];
  }

  // U[d][vd] = ebl[d] * sum_i ke2[i][d] * v[i][vd] ; 2x4 tiles over (d,vd)
  {
    int td = tid >> 4, tv = tid & 15;
    int d0 = td * 2, v0 = tv * 4;
    float u[2][4] = {};
    for (int i = 0; i < 64; ++i) {
      float kv[2], vv[4];
#pragma unroll
      for (int x = 0; x < 2; ++x) kv[x] = sk[i * 32 + d0 + x];
#pragma unroll
      for (int y = 0; y < 4; ++y) vv[y] = sv[i * 64 + v0 + y];
#pragma unroll
      for (int x = 0; x < 2; ++x)
#pragma unroll
        for (int y = 0; y < 4; ++y) u[x][y] += kv[x] * vv[y];
    }
    size_t ub = ((size_t)c * 32 + bh) * (32 * 64);
#pragma unroll
    for (int x = 0; x < 2; ++x)
#pragma unroll
      for (int y = 0; y < 4; ++y)
        U[ub + (d0 + x) * 64 + v0 + y] = u[x][y] * ebl[d0 + x];
  }
}

// ---------------- phase 2: inter-chunk state recurrence ----------------
// S[c] = state before chunk c.  S[0]=0; S[c+1] = dvec[c]*S[c] + U[c]

__global__ __launch_bounds__(256) void k_phase2(const float* __restrict__ U,
                                                const float* __restrict__ dvec,
                                                float* __restrict__ S) {
  int idx = blockIdx.x * 256 + threadIdx.x;   // B*H*HK*HV = 65536
  int bh = idx >> 11, r = idx & 2047;
  int d = r >> 6;
  float run = 0.0f;
  for (int c = 0; c < NC_; ++c) {
    size_t o = ((size_t)c * 32 + bh) * 2048 + r;
    S[o] = run;
    run = dvec[((size_t)c * 32 + bh) * 32 + d] * run + U[o];
  }
}

// ---------------- phase 3: o += qe @ S_c ----------------

__global__ __launch_bounds__(256) void k_phase3(const float* __restrict__ qe,
                                                const float* __restrict__ S,
                                                float* __restrict__ o) {
  const int bi = blockIdx.x;
  const int c = bi >> 5, bh = bi & 31;
  const int b = bh >> 4, h = bh & 15;
  const int tid = threadIdx.x;
  __shared__ float sq[64 * 32];
  __shared__ float sS[32 * 64];
  const size_t rq = (size_t)(b * T_ + c * 64) * KD_ + h * 32;
  const size_t rv = (size_t)(b * T_ + c * 64) * VD_ + h * 64;
  const size_t sbase = ((size_t)c * 32 + bh) * 2048;
#pragma unroll
  for (int s = 0; s < 8; ++s) {
    int e = tid + s * 256;
    int i = e >> 5, d = e & 31;
    sq[e] = qe[rq + (size_t)i * KD_ + d];
    sS[e] = S[sbase + e];
  }
  __syncthreads();
  int ti = tid >> 4, tv = tid & 15;
  int i0 = ti * 4, v0 = tv * 4;
  float acc[4][4] = {};
  for (int d = 0; d < 32; ++d) {
    float qv[4], sv4[4];
#pragma unroll
    for (int x = 0; x < 4; ++x) qv[x] = sq[(i0 + x) * 32 + d];
#pragma unroll
    for (int y = 0; y < 4; ++y) sv4[y] = sS[d * 64 + v0 + y];
#pragma unroll
    for (int x = 0; x < 4; ++x)
#pragma unroll
      for (int y = 0; y < 4; ++y) acc[x][y] += qv[x] * sv4[y];
  }
#pragma unroll
  for (int x = 0; x < 4; ++x)
#pragma unroll
    for (int y = 0; y < 4; ++y) {
      size_t off = rv + (size_t)(i0 + x) * VD_ + v0 + y;
      o[off] += acc[x][y];
    }
}

// ---------------- RMS norm + swish gate -> bf16 y ----------------

__global__ __launch_bounds__(256) void k_rms_gate(const float* __restrict__ o,
                                                  const float* __restrict__ g,
                                                  const float* __restrict__ norm_w,
                                                  unsigned short* __restrict__ y) {
  int row = blockIdx.x * 4 + (threadIdx.x >> 6);   // over M*H rows of 64
  int lane = threadIdx.x & 63;
  size_t off = (size_t)row * 64 + lane;
  float ov = o[off];
  float s = ov * ov;
#pragma unroll
  for (int d = 32; d; d >>= 1) s += __shfl_xor(s, d, 64);
  float rs = rsqrtf(s * (1.0f / 64.0f) + EPS_);
  float gv = g[off];
  float sw = gv / (1.0f + expf(-gv));
  y[off] = f2bf(ov * rs * norm_w[lane] * sw);
}

// ---------------- launch ----------------

extern "C" void kernel_launch(void* const* d_in, const int* in_sizes, int n_in,
                              void* d_out, int out_size, void* d_ws, size_t ws_size,
                              hipStream_t stream) {
  const float* x    = (const float*)d_in[0];
  const float* Wq   = (const float*)d_in[1];
  const float* Wk   = (const float*)d_in[2];
  const float* Wv   = (const float*)d_in[3];
  const float* Wgk1 = (const float*)d_in[4];
  const float* Wgk2 = (const float*)d_in[5];
  const float* bgk  = (const float*)d_in[6];
  const float* Wg   = (const float*)d_in[7];
  const float* nw   = (const float*)d_in[8];
  const float* Wo   = (const float*)d_in[9];
  float* out = (float*)d_out;

  char* p = (char*)d_ws;
  unsigned short* xb    = (unsigned short*)p;            p += (size_t)M_ * D_ * 2;
  unsigned short* wqT   = (unsigned short*)p;            p += (size_t)KD_ * D_ * 2;
  unsigned short* wkT   = (unsigned short*)p;            p += (size_t)KD_ * D_ * 2;
  unsigned short* wvT   = (unsigned short*)p;            p += (size_t)VD_ * D_ * 2;
  unsigned short* wgT   = (unsigned short*)p;            p += (size_t)VD_ * D_ * 2;
  unsigned short* woT   = (unsigned short*)p;            p += (size_t)D_ * VD_ * 2;
  unsigned short* wg1P  = (unsigned short*)p;            p += (size_t)128 * D_ * 2;
  float* qbuf  = (float*)p;  p += (size_t)M_ * KD_ * 4;
  float* kbuf  = (float*)p;  p += (size_t)M_ * KD_ * 4;
  float* gkbuf = (float*)p;  p += (size_t)M_ * KD_ * 4;
  float* vbuf  = (float*)p;  p += (size_t)M_ * VD_ * 4;   // later holds o
  float* gbuf  = (float*)p;  p += (size_t)M_ * VD_ * 4;
  float* glow  = (float*)p;  p += (size_t)M_ * 128 * 4;
  float* Ubuf  = (float*)p;  p += (size_t)NC_ * 32 * 2048 * 4;
  float* Sbuf  = (float*)p;  p += (size_t)NC_ * 32 * 2048 * 4;
  float* dbuf  = (float*)p;  p += (size_t)NC_ * 32 * 32 * 4;
  unsigned short* ybuf = (unsigned short*)p;  p += (size_t)M_ * VD_ * 2;

  // conversions
  k_f32_to_bf16<<<(M_ * D_ / 4) / 256, 256, 0, stream>>>(x, xb, M_ * D_);
  k_transpose_bf16<<<dim3(KD_/32, D_/32), 256, 0, stream>>>(Wq, wqT, D_, KD_);
  k_transpose_bf16<<<dim3(KD_/32, D_/32), 256, 0, stream>>>(Wk, wkT, D_, KD_);
  k_transpose_bf16<<<dim3(VD_/32, D_/32), 256, 0, stream>>>(Wv, wvT, D_, VD_);
  k_transpose_bf16<<<dim3(VD_/32, D_/32), 256, 0, stream>>>(Wg, wgT, D_, VD_);
  k_transpose_bf16<<<dim3(D_/32, VD_/32), 256, 0, stream>>>(Wo, woT, VD_, D_);
  k_pad_wgk1<<<(128 * D_) / 256, 256, 0, stream>>>(Wgk1, wg1P);

  // projections
  k_gemm_bt<<<dim3(KD_/128, M_/128), 256, 0, stream>>>(xb, wqT, qbuf, M_, KD_, D_);
  k_gemm_bt<<<dim3(KD_/128, M_/128), 256, 0, stream>>>(xb, wkT, kbuf, M_, KD_, D_);
  k_gemm_bt<<<dim3(VD_/128, M_/128), 256, 0, stream>>>(xb, wvT, vbuf, M_, VD_, D_);
  k_gemm_bt<<<dim3(VD_/128, M_/128), 256, 0, stream>>>(xb, wgT, gbuf, M_, VD_, D_);
  k_gemm_bt<<<dim3(1,       M_/128), 256, 0, stream>>>(xb, wg1P, glow, M_, 128, D_);

  // gate nonlinearity
  k_gate<<<(M_ * KD_) / 256, 256, 0, stream>>>(glow, Wgk2, bgk, gkbuf);

  // attention
  k_phase1<<<NC_ * 32, 256, 0, stream>>>(qbuf, kbuf, gkbuf, vbuf, Ubuf, dbuf);
  k_phase2<<<(32 * 2048) / 256, 256, 0, stream>>>(Ubuf, dbuf, Sbuf);
  k_phase3<<<NC_ * 32, 256, 0, stream>>>(qbuf, Sbuf, vbuf);

  // epilogue
  k_rms_gate<<<(M_ * H_) / 4, 256, 0, stream>>>(vbuf, gbuf, nw, ybuf);
  k_gemm_bt<<<dim3(D_/128, M_/128), 256, 0, stream>>>(ybuf, woT, out, M_, D_, VD_);
}

// Round 2
// 354.695 us; speedup vs baseline: 1.8159x; 1.8159x over previous
//
#include <hip/hip_runtime.h>
#include <cstddef>

#define B_   2
#define T_   4096
#define D_   1024
#define H_   16
#define KD_  512
#define VD_  1024
#define HK_  32
#define HV_  64
#define NC_  64          // T/CHUNK
#define M_   (B_*T_)     // 8192
#define GR_  16
#define EPS_ 1e-5f
#define SCALE_ 0.17677669529663687f  // 32^-0.5
#define GNORM_INV_ (1.0f/16.0f)

// fused projection layout: cols [0,512)=q, [512,1024)=k, [1024,2048)=v,
// [2048,3072)=g, [3072,3200)=glow (only first 16 weight rows nonzero)
#define NF_   3200
#define Q0_   0
#define K0_   512
#define V0_   1024
#define G0_   2048
#define GL0_  3072

typedef __attribute__((ext_vector_type(8))) __bf16 bf16x8;
typedef __attribute__((ext_vector_type(4))) float f32x4;

__device__ inline unsigned short f2bf(float f) {
  unsigned int u = __float_as_uint(f);
  u = (u + 0x7fffu + ((u >> 16) & 1u)) >> 16;
  return (unsigned short)u;
}

__device__ __forceinline__ void gload_lds16(const unsigned short* g, unsigned short* l) {
  __builtin_amdgcn_global_load_lds(
      (const __attribute__((address_space(1))) unsigned int*)g,
      (__attribute__((address_space(3))) unsigned int*)l, 16, 0, 0);
}

// ---------------- elementwise conversions ----------------

__global__ __launch_bounds__(256) void k_f32_to_bf16(const float* __restrict__ in,
                                                     unsigned short* __restrict__ out, int n4) {
  int i = (blockIdx.x * 256 + threadIdx.x) * 4;
  float4 f = *(const float4*)(in + i);
  ushort4 o;
  o.x = f2bf(f.x); o.y = f2bf(f.y); o.z = f2bf(f.z); o.w = f2bf(f.w);
  *(ushort4*)(out + i) = o;
}

// in: K x N f32 row-major; out: N x K bf16 row-major
__global__ __launch_bounds__(256) void k_transpose_bf16(const float* __restrict__ in,
                                                        unsigned short* __restrict__ out,
                                                        int K, int N) {
  __shared__ float tile[32][33];
  int n0 = blockIdx.x * 32, k0 = blockIdx.y * 32;
  int tx = threadIdx.x & 31, ty = threadIdx.x >> 5;   // 32 x 8
#pragma unroll
  for (int p = 0; p < 4; ++p)
    tile[ty + p*8][tx] = in[(size_t)(k0 + ty + p*8) * N + n0 + tx];
  __syncthreads();
#pragma unroll
  for (int p = 0; p < 4; ++p)
    out[(size_t)(n0 + ty + p*8) * K + k0 + tx] = f2bf(tile[tx][ty + p*8]);
}

// Wgk1: D x GR f32 -> padded transposed 128 x D bf16 (rows >= GR are zero)
__global__ __launch_bounds__(256) void k_pad_wgk1(const float* __restrict__ w,
                                                  unsigned short* __restrict__ out) {
  int idx = blockIdx.x * 256 + threadIdx.x;     // 128 * 1024
  int n = idx >> 10, kk = idx & 1023;
  float v = (n < GR_) ? w[kk * GR_ + n] : 0.0f;
  out[idx] = f2bf(v);
}

// ---------------- bf16 MFMA GEMM: C(MxN,f32) = A(MxK) * Bt(NxK)^T ----------------
// 128x128 tile, BK=64, 256 threads (4 waves 2x2), 16x16x32 MFMA.
// Staging via global_load_lds width=16; XOR swizzle applied on the global
// source column (lane permutation within a 128B segment) so LDS lands
// pre-swizzled -> conflict-free ds_read_b128 fragment reads.

__global__ __launch_bounds__(256) void k_gemm_bt(const unsigned short* __restrict__ A,
                                                 const unsigned short* __restrict__ Bt,
                                                 float* __restrict__ C,
                                                 int M, int N, int K) {
  __shared__ __align__(16) unsigned short sA[128 * 64];
  __shared__ __align__(16) unsigned short sB[128 * 64];
  const int tid  = threadIdx.x;
  const int lane = tid & 63;
  const int wave = tid >> 6;
  const int wr = wave >> 1, wc = wave & 1;
  const int quad = lane >> 4, l16 = lane & 15;
  const int bm0 = blockIdx.y * 128, bn0 = blockIdx.x * 128;

  // staging: wave handles rows wave*8 + it*32 + (lane>>3); lane fetches the
  // XOR-swizzled k-group so LDS slot (row, pos) holds global group pos^row&7
  const int lrow = lane >> 3;                      // 0..7 (== row & 7)
  const int gcol = ((lane & 7) ^ lrow) * 8;        // swizzled source column
  const unsigned short* ga = A  + (size_t)(bm0 + wave * 8 + lrow) * K + gcol;
  const unsigned short* gb = Bt + (size_t)(bn0 + wave * 8 + lrow) * K + gcol;
  unsigned short* la = sA + wave * 8 * 64;
  unsigned short* lb = sB + wave * 8 * 64;

  f32x4 acc[4][4] = {};

  for (int k0 = 0; k0 < K; k0 += 64) {
#pragma unroll
    for (int it = 0; it < 4; ++it) {
      gload_lds16(ga + k0 + (size_t)it * 32 * K, la + it * 32 * 64);
      gload_lds16(gb + k0 + (size_t)it * 32 * K, lb + it * 32 * 64);
    }
    __syncthreads();   // drains vmcnt(0): loads landed, LDS ready
#pragma unroll
    for (int kk = 0; kk < 2; ++kk) {
      bf16x8 af[4], bfv[4];
#pragma unroll
      for (int i = 0; i < 4; ++i) {
        int row = wr * 64 + i * 16 + l16;
        int g = (kk * 4 + quad) ^ (row & 7);
        af[i] = *(const bf16x8*)(sA + row * 64 + g * 8);
      }
#pragma unroll
      for (int j = 0; j < 4; ++j) {
        int row = wc * 64 + j * 16 + l16;
        int g = (kk * 4 + quad) ^ (row & 7);
        bfv[j] = *(const bf16x8*)(sB + row * 64 + g * 8);
      }
#pragma unroll
      for (int i = 0; i < 4; ++i)
#pragma unroll
        for (int j = 0; j < 4; ++j)
          acc[i][j] = __builtin_amdgcn_mfma_f32_16x16x32_bf16(af[i], bfv[j], acc[i][j], 0, 0, 0);
    }
    __syncthreads();   // all waves done reading before next overwrite
  }

#pragma unroll
  for (int i = 0; i < 4; ++i) {
    int row0 = bm0 + wr * 64 + i * 16 + quad * 4;
#pragma unroll
    for (int j = 0; j < 4; ++j) {
      int col = bn0 + wc * 64 + j * 16 + l16;
#pragma unroll
      for (int r = 0; r < 4; ++r)
        C[(size_t)(row0 + r) * N + col] = acc[i][j][r];
    }
  }
}

// ---------------- gate: gk = log_sigmoid(glow @ Wgk2 + bgk) / 16 ----------------

__global__ __launch_bounds__(256) void k_gate(const float* __restrict__ pbuf,
                                              const float* __restrict__ Wgk2,
                                              const float* __restrict__ bgk,
                                              float* __restrict__ gk) {
  int idx = blockIdx.x * 256 + threadIdx.x;   // M * KD
  int t = idx >> 9, n = idx & 511;
  const float* gr = pbuf + (size_t)t * NF_ + GL0_;
  float s = bgk[n];
#pragma unroll
  for (int r = 0; r < GR_; ++r) s += gr[r] * Wgk2[r * KD_ + n];
  float ls = fminf(s, 0.0f) - log1pf(expf(-fabsf(s)));
  gk[idx] = ls * GNORM_INV_;
}

// ---------------- attention phase 1: per chunk-head intra work ----------------
// pbuf: q -> qe in place; v -> o_intra in place.
// U[(c*32+bh)*2048 + d*64 + vd], dvec[(c*32+bh)*32 + d] = exp(b_last)

__global__ __launch_bounds__(256) void k_phase1(float* __restrict__ pbuf,
                                                const float* __restrict__ gkbuf,
                                                float* __restrict__ U,
                                                float* __restrict__ dvec) {
  const int bi = blockIdx.x;
  const int c = bi >> 5, bh = bi & 31;
  const int b = bh >> 4, h = bh & 15;
  const int tid = threadIdx.x;

  __shared__ float sq[64 * 32];
  __shared__ float sk[64 * 32];
  __shared__ float sb[64 * 32];
  __shared__ float sv[64 * 64];
  __shared__ float sA[64 * 65];
  __shared__ float ebl[32];

  const size_t rq = (size_t)(b * T_ + c * 64) * NF_ + Q0_ + h * 32;
  const size_t rk = (size_t)(b * T_ + c * 64) * NF_ + K0_ + h * 32;
  const size_t rg = (size_t)(b * T_ + c * 64) * KD_ + h * 32;
  const size_t rv = (size_t)(b * T_ + c * 64) * NF_ + V0_ + h * 64;

#pragma unroll
  for (int s = 0; s < 8; ++s) {
    int e = tid + s * 256;
    int i = e >> 5, d = e & 31;
    sq[e] = pbuf[rq + (size_t)i * NF_ + d];
    sk[e] = pbuf[rk + (size_t)i * NF_ + d];
    sb[e] = gkbuf[rg + (size_t)i * KD_ + d];
  }
#pragma unroll
  for (int s = 0; s < 16; ++s) {
    int e = tid + s * 256;
    int i = e >> 6, vd = e & 63;
    sv[e] = pbuf[rv + (size_t)i * NF_ + vd];
  }
  __syncthreads();

  if (tid < 32) {
    float run = 0.0f;
    for (int i = 0; i < 64; ++i) { run += sb[i * 32 + tid]; sb[i * 32 + tid] = run; }
    float e = expf(run);
    ebl[tid] = e;
    dvec[((size_t)c * 32 + bh) * 32 + tid] = e;
  }
  __syncthreads();

#pragma unroll
  for (int s = 0; s < 8; ++s) {
    int e = tid + s * 256;
    int i = e >> 5, d = e & 31;
    float bb = sb[e];
    float qe = sq[e] * expf(bb) * SCALE_;
    sq[e] = qe;
    pbuf[rq + (size_t)i * NF_ + d] = qe;
    sk[e] = sk[e] * expf(-bb);   // ke2
  }
  __syncthreads();

  // A = qe @ ke2^T, masked lower-tri.
  {
    int ti = tid >> 4, tj = tid & 15;
    int i0 = ti * 4, j0 = tj * 4;
    float a[4][4] = {};
    if (j0 <= i0 + 3) {
      for (int dd = 0; dd < 32; ++dd) {
        int d = (dd + tid) & 31;
        float qv[4], kv[4];
#pragma unroll
        for (int x = 0; x < 4; ++x) qv[x] = sq[(i0 + x) * 32 + d];
#pragma unroll
        for (int y = 0; y < 4; ++y) kv[y] = sk[(j0 + y) * 32 + d];
#pragma unroll
        for (int x = 0; x < 4; ++x)
#pragma unroll
          for (int y = 0; y < 4; ++y) a[x][y] += qv[x] * kv[y];
      }
    }
#pragma unroll
    for (int x = 0; x < 4; ++x)
#pragma unroll
      for (int y = 0; y < 4; ++y)
        sA[(i0 + x) * 65 + j0 + y] = (j0 + y <= i0 + x) ? a[x][y] : 0.0f;
  }
  __syncthreads();

  // o_intra = A @ v
  {
    int ti = tid >> 4, tv = tid & 15;
    int i0 = ti * 4, v0 = tv * 4;
    float o[4][4] = {};
    int jmax = i0 + 3;
    for (int j = 0; j <= jmax; ++j) {
      float av[4], vv[4];
#pragma unroll
      for (int x = 0; x < 4; ++x) av[x] = sA[(i0 + x) * 65 + j];
#pragma unroll
      for (int y = 0; y < 4; ++y) vv[y] = sv[j * 64 + v0 + y];
#pragma unroll
      for (int x = 0; x < 4; ++x)
#pragma unroll
        for (int y = 0; y < 4; ++y) o[x][y] += av[x] * vv[y];
    }
#pragma unroll
    for (int x = 0; x < 4; ++x)
#pragma unroll
      for (int y = 0; y < 4; ++y)
        pbuf[rv + (size_t)(i0 + x) * NF_ + v0 + y] = o[x][y];
  }

  // U[d][vd] = ebl[d] * sum_i ke2[i][d] * v[i][vd]
  {
    int td = tid >> 4, tv = tid & 15;
    int d0 = td * 2, v0 = tv * 4;
    float u[2][4] = {};
    for (int i = 0; i < 64; ++i) {
      float kv[2], vv[4];
#pragma unroll
      for (int x = 0; x < 2; ++x) kv[x] = sk[i * 32 + d0 + x];
#pragma unroll
      for (int y = 0; y < 4; ++y) vv[y] = sv[i * 64 + v0 + y];
#pragma unroll
      for (int x = 0; x < 2; ++x)
#pragma unroll
        for (int y = 0; y < 4; ++y) u[x][y] += kv[x] * vv[y];
    }
    size_t ub = ((size_t)c * 32 + bh) * (32 * 64);
#pragma unroll
    for (int x = 0; x < 2; ++x)
#pragma unroll
      for (int y = 0; y < 4; ++y)
        U[ub + (d0 + x) * 64 + v0 + y] = u[x][y] * ebl[d0 + x];
  }
}

// ---------------- phase 2: inter-chunk state recurrence ----------------

__global__ __launch_bounds__(256) void k_phase2(const float* __restrict__ U,
                                                const float* __restrict__ dvec,
                                                float* __restrict__ S) {
  int idx = blockIdx.x * 256 + threadIdx.x;   // B*H*HK*HV = 65536
  int bh = idx >> 11, r = idx & 2047;
  int d = r >> 6;
  float run = 0.0f;
  for (int c = 0; c < NC_; ++c) {
    size_t o = ((size_t)c * 32 + bh) * 2048 + r;
    S[o] = run;
    run = dvec[((size_t)c * 32 + bh) * 32 + d] * run + U[o];
  }
}

// ---------------- phase 3: o += qe @ S_c ----------------

__global__ __launch_bounds__(256) void k_phase3(float* __restrict__ pbuf,
                                                const float* __restrict__ S) {
  const int bi = blockIdx.x;
  const int c = bi >> 5, bh = bi & 31;
  const int b = bh >> 4, h = bh & 15;
  const int tid = threadIdx.x;
  __shared__ float sq[64 * 32];
  __shared__ float sS[32 * 64];
  const size_t rq = (size_t)(b * T_ + c * 64) * NF_ + Q0_ + h * 32;
  const size_t rv = (size_t)(b * T_ + c * 64) * NF_ + V0_ + h * 64;
  const size_t sbase = ((size_t)c * 32 + bh) * 2048;
#pragma unroll
  for (int s = 0; s < 8; ++s) {
    int e = tid + s * 256;
    int i = e >> 5, d = e & 31;
    sq[e] = pbuf[rq + (size_t)i * NF_ + d];
    sS[e] = S[sbase + e];
  }
  __syncthreads();
  int ti = tid >> 4, tv = tid & 15;
  int i0 = ti * 4, v0 = tv * 4;
  float acc[4][4] = {};
  for (int d = 0; d < 32; ++d) {
    float qv[4], sv4[4];
#pragma unroll
    for (int x = 0; x < 4; ++x) qv[x] = sq[(i0 + x) * 32 + d];
#pragma unroll
    for (int y = 0; y < 4; ++y) sv4[y] = sS[d * 64 + v0 + y];
#pragma unroll
    for (int x = 0; x < 4; ++x)
#pragma unroll
      for (int y = 0; y < 4; ++y) acc[x][y] += qv[x] * sv4[y];
  }
#pragma unroll
  for (int x = 0; x < 4; ++x)
#pragma unroll
    for (int y = 0; y < 4; ++y) {
      size_t off = rv + (size_t)(i0 + x) * NF_ + v0 + y;
      pbuf[off] += acc[x][y];
    }
}

// ---------------- RMS norm + swish gate -> bf16 y ----------------

__global__ __launch_bounds__(256) void k_rms_gate(const float* __restrict__ pbuf,
                                                  const float* __restrict__ norm_w,
                                                  unsigned short* __restrict__ y) {
  int row = blockIdx.x * 4 + (threadIdx.x >> 6);   // over M*H rows of 64
  int lane = threadIdx.x & 63;
  int m = row >> 4, h = row & 15;
  size_t oo = (size_t)m * NF_ + V0_ + h * 64 + lane;
  size_t og = (size_t)m * NF_ + G0_ + h * 64 + lane;
  float ov = pbuf[oo];
  float s = ov * ov;
#pragma unroll
  for (int d = 32; d; d >>= 1) s += __shfl_xor(s, d, 64);
  float rs = rsqrtf(s * (1.0f / 64.0f) + EPS_);
  float gv = pbuf[og];
  float sw = gv / (1.0f + expf(-gv));
  y[(size_t)row * 64 + lane] = f2bf(ov * rs * norm_w[lane] * sw);
}

// ---------------- launch ----------------

extern "C" void kernel_launch(void* const* d_in, const int* in_sizes, int n_in,
                              void* d_out, int out_size, void* d_ws, size_t ws_size,
                              hipStream_t stream) {
  const float* x    = (const float*)d_in[0];
  const float* Wq   = (const float*)d_in[1];
  const float* Wk   = (const float*)d_in[2];
  const float* Wv   = (const float*)d_in[3];
  const float* Wgk1 = (const float*)d_in[4];
  const float* Wgk2 = (const float*)d_in[5];
  const float* bgk  = (const float*)d_in[6];
  const float* Wg   = (const float*)d_in[7];
  const float* nw   = (const float*)d_in[8];
  const float* Wo   = (const float*)d_in[9];
  float* out = (float*)d_out;

  char* p = (char*)d_ws;
  unsigned short* xb   = (unsigned short*)p;  p += (size_t)M_ * D_ * 2;
  unsigned short* Wcat = (unsigned short*)p;  p += (size_t)NF_ * D_ * 2;
  unsigned short* woT  = (unsigned short*)p;  p += (size_t)D_ * VD_ * 2;
  float* pbuf  = (float*)p;  p += (size_t)M_ * NF_ * 4;
  float* gkbuf = (float*)p;  p += (size_t)M_ * KD_ * 4;
  float* Ubuf  = (float*)p;  p += (size_t)NC_ * 32 * 2048 * 4;
  float* Sbuf  = (float*)p;  p += (size_t)NC_ * 32 * 2048 * 4;
  float* dbuf  = (float*)p;  p += (size_t)NC_ * 32 * 32 * 4;
  unsigned short* ybuf = (unsigned short*)p;  p += (size_t)M_ * VD_ * 2;

  // conversions
  k_f32_to_bf16<<<(M_ * D_ / 4) / 256, 256, 0, stream>>>(x, xb, M_ * D_);
  k_transpose_bf16<<<dim3(KD_/32, D_/32), 256, 0, stream>>>(Wq, Wcat + (size_t)Q0_ * D_, D_, KD_);
  k_transpose_bf16<<<dim3(KD_/32, D_/32), 256, 0, stream>>>(Wk, Wcat + (size_t)K0_ * D_, D_, KD_);
  k_transpose_bf16<<<dim3(VD_/32, D_/32), 256, 0, stream>>>(Wv, Wcat + (size_t)V0_ * D_, D_, VD_);
  k_transpose_bf16<<<dim3(VD_/32, D_/32), 256, 0, stream>>>(Wg, Wcat + (size_t)G0_ * D_, D_, VD_);
  k_transpose_bf16<<<dim3(D_/32, VD_/32), 256, 0, stream>>>(Wo, woT, VD_, D_);
  k_pad_wgk1<<<(128 * D_) / 256, 256, 0, stream>>>(Wgk1, Wcat + (size_t)GL0_ * D_);

  // fused projections: q|k|v|g|glow in one GEMM (1600 blocks)
  k_gemm_bt<<<dim3(NF_/128, M_/128), 256, 0, stream>>>(xb, Wcat, pbuf, M_, NF_, D_);

  // gate nonlinearity
  k_gate<<<(M_ * KD_) / 256, 256, 0, stream>>>(pbuf, Wgk2, bgk, gkbuf);

  // attention
  k_phase1<<<NC_ * 32, 256, 0, stream>>>(pbuf, gkbuf, Ubuf, dbuf);
  k_phase2<<<(32 * 2048) / 256, 256, 0, stream>>>(Ubuf, dbuf, Sbuf);
  k_phase3<<<NC_ * 32, 256, 0, stream>>>(pbuf, Sbuf);

  // epilogue
  k_rms_gate<<<(M_ * H_) / 4, 256, 0, stream>>>(pbuf, nw, ybuf);
  k_gemm_bt<<<dim3(D_/128, M_/128), 256, 0, stream>>>(ybuf, woT, out, M_, D_, VD_);
}

// Round 3
// 325.679 us; speedup vs baseline: 1.9777x; 1.0891x over previous
//
#include <hip/hip_runtime.h>
#include <cstddef>

#define B_   2
#define T_   4096
#define D_   1024
#define H_   16
#define KD_  512
#define VD_  1024
#define HK_  32
#define HV_  64
#define NC_  64          // T/CHUNK
#define M_   (B_*T_)     // 8192
#define GR_  16
#define EPS_ 1e-5f
#define SCALE_ 0.17677669529663687f  // 32^-0.5
#define GNORM_INV_ (1.0f/16.0f)

// fused projection layout: cols [0,512)=q, [512,1024)=k, [1024,2048)=v,
// [2048,3072)=g, [3072,3200)=glow (only first 16 weight rows nonzero)
#define NF_   3200
#define Q0_   0
#define K0_   512
#define V0_   1024
#define G0_   2048
#define GL0_  3072

typedef __attribute__((ext_vector_type(8))) __bf16 bf16x8;
typedef __attribute__((ext_vector_type(4))) float f32x4;

__device__ inline unsigned short f2bf(float f) {
  unsigned int u = __float_as_uint(f);
  u = (u + 0x7fffu + ((u >> 16) & 1u)) >> 16;
  return (unsigned short)u;
}
__device__ inline float bf2f(unsigned short u) {
  return __uint_as_float((unsigned int)u << 16);
}

__device__ __forceinline__ void gload_lds16(const unsigned short* g, unsigned short* l) {
  __builtin_amdgcn_global_load_lds(
      (const __attribute__((address_space(1))) unsigned int*)g,
      (__attribute__((address_space(3))) unsigned int*)l, 16, 0, 0);
}

// ---------------- elementwise conversions ----------------

__global__ __launch_bounds__(256) void k_f32_to_bf16(const float* __restrict__ in,
                                                     unsigned short* __restrict__ out, int n4) {
  int i = (blockIdx.x * 256 + threadIdx.x) * 4;
  float4 f = *(const float4*)(in + i);
  ushort4 o;
  o.x = f2bf(f.x); o.y = f2bf(f.y); o.z = f2bf(f.z); o.w = f2bf(f.w);
  *(ushort4*)(out + i) = o;
}

// all five weight transposes in one launch. z selects the matrix.
// in: K x N f32 row-major; out: N x K bf16 row-major
__global__ __launch_bounds__(256) void k_transpose_all(const float* __restrict__ Wq,
                                                       const float* __restrict__ Wk,
                                                       const float* __restrict__ Wv,
                                                       const float* __restrict__ Wg,
                                                       const float* __restrict__ Wo,
                                                       unsigned short* __restrict__ Wcat,
                                                       unsigned short* __restrict__ woT) {
  __shared__ float tile[32][33];
  const float* in; unsigned short* out; int N;
  switch (blockIdx.z) {
    case 0: in = Wq; out = Wcat + (size_t)Q0_ * D_; N = 512;  break;
    case 1: in = Wk; out = Wcat + (size_t)K0_ * D_; N = 512;  break;
    case 2: in = Wv; out = Wcat + (size_t)V0_ * D_; N = 1024; break;
    case 3: in = Wg; out = Wcat + (size_t)G0_ * D_; N = 1024; break;
    default: in = Wo; out = woT;                     N = 1024; break;
  }
  int n0 = blockIdx.x * 32, k0 = blockIdx.y * 32;
  if (n0 >= N) return;
  int tx = threadIdx.x & 31, ty = threadIdx.x >> 5;   // 32 x 8
#pragma unroll
  for (int p = 0; p < 4; ++p)
    tile[ty + p*8][tx] = in[(size_t)(k0 + ty + p*8) * N + n0 + tx];
  __syncthreads();
#pragma unroll
  for (int p = 0; p < 4; ++p)
    out[(size_t)(n0 + ty + p*8) * 1024 + k0 + tx] = f2bf(tile[tx][ty + p*8]);
}

// Wgk1: D x GR f32 -> padded transposed 128 x D bf16 (rows >= GR are zero)
__global__ __launch_bounds__(256) void k_pad_wgk1(const float* __restrict__ w,
                                                  unsigned short* __restrict__ out) {
  int idx = blockIdx.x * 256 + threadIdx.x;     // 128 * 1024
  int n = idx >> 10, kk = idx & 1023;
  float v = (n < GR_) ? w[kk * GR_ + n] : 0.0f;
  out[idx] = f2bf(v);
}

// ---------------- bf16 MFMA GEMM: C(MxN) = A(MxK) * Bt(NxK)^T ----------------
// 128x128 tile, BK=64, 256 threads (4 waves 2x2), 16x16x32 MFMA.
// global_load_lds width=16 with the XOR swizzle applied on the global source
// column (lane permutation within a 128B segment) -> conflict-free ds_read_b128.
// OutT = unsigned short (bf16 store) or float.

template <typename OutT>
__global__ __launch_bounds__(256) void k_gemm_bt(const unsigned short* __restrict__ A,
                                                 const unsigned short* __restrict__ Bt,
                                                 OutT* __restrict__ C,
                                                 int M, int N, int K) {
  __shared__ __align__(16) unsigned short sA[128 * 64];
  __shared__ __align__(16) unsigned short sB[128 * 64];
  const int tid  = threadIdx.x;
  const int lane = tid & 63;
  const int wave = tid >> 6;
  const int wr = wave >> 1, wc = wave & 1;
  const int quad = lane >> 4, l16 = lane & 15;
  const int bm0 = blockIdx.y * 128, bn0 = blockIdx.x * 128;

  const int lrow = lane >> 3;                      // 0..7 (== row & 7)
  const int gcol = ((lane & 7) ^ lrow) * 8;        // swizzled source column
  const unsigned short* ga = A  + (size_t)(bm0 + wave * 8 + lrow) * K + gcol;
  const unsigned short* gb = Bt + (size_t)(bn0 + wave * 8 + lrow) * K + gcol;
  unsigned short* la = sA + wave * 8 * 64;
  unsigned short* lb = sB + wave * 8 * 64;

  f32x4 acc[4][4] = {};

  for (int k0 = 0; k0 < K; k0 += 64) {
#pragma unroll
    for (int it = 0; it < 4; ++it) {
      gload_lds16(ga + k0 + (size_t)it * 32 * K, la + it * 32 * 64);
      gload_lds16(gb + k0 + (size_t)it * 32 * K, lb + it * 32 * 64);
    }
    __syncthreads();
#pragma unroll
    for (int kk = 0; kk < 2; ++kk) {
      bf16x8 af[4], bfv[4];
#pragma unroll
      for (int i = 0; i < 4; ++i) {
        int row = wr * 64 + i * 16 + l16;
        int g = (kk * 4 + quad) ^ (row & 7);
        af[i] = *(const bf16x8*)(sA + row * 64 + g * 8);
      }
#pragma unroll
      for (int j = 0; j < 4; ++j) {
        int row = wc * 64 + j * 16 + l16;
        int g = (kk * 4 + quad) ^ (row & 7);
        bfv[j] = *(const bf16x8*)(sB + row * 64 + g * 8);
      }
#pragma unroll
      for (int i = 0; i < 4; ++i)
#pragma unroll
        for (int j = 0; j < 4; ++j)
          acc[i][j] = __builtin_amdgcn_mfma_f32_16x16x32_bf16(af[i], bfv[j], acc[i][j], 0, 0, 0);
    }
    __syncthreads();
  }

#pragma unroll
  for (int i = 0; i < 4; ++i) {
    int row0 = bm0 + wr * 64 + i * 16 + quad * 4;
#pragma unroll
    for (int j = 0; j < 4; ++j) {
      int col = bn0 + wc * 64 + j * 16 + l16;
#pragma unroll
      for (int r = 0; r < 4; ++r) {
        float v = acc[i][j][r];
        if constexpr (sizeof(OutT) == 2)
          C[(size_t)(row0 + r) * N + col] = (OutT)f2bf(v);
        else
          C[(size_t)(row0 + r) * N + col] = (OutT)v;
      }
    }
  }
}

// ---------------- gate: gk = log_sigmoid(glow @ Wgk2 + bgk) / 16 ----------------

__global__ __launch_bounds__(256) void k_gate(const unsigned short* __restrict__ pbuf,
                                              const float* __restrict__ Wgk2,
                                              const float* __restrict__ bgk,
                                              float* __restrict__ gk) {
  int idx = blockIdx.x * 256 + threadIdx.x;   // M * KD
  int t = idx >> 9, n = idx & 511;
  const unsigned short* gr = pbuf + (size_t)t * NF_ + GL0_;
  float s = bgk[n];
#pragma unroll
  for (int r = 0; r < GR_; ++r) s += bf2f(gr[r]) * Wgk2[r * KD_ + n];
  // log_sigmoid(s) = min(s,0) - log1p(exp(-|s|))
  float ls = fminf(s, 0.0f) - __logf(1.0f + __expf(-fabsf(s)));
  gk[idx] = ls * GNORM_INV_;
}

// ---------------- attention phase 1: per chunk-head intra work ----------------
// pbuf(bf16): q -> qe in place. o_intra -> obuf (f32).
// U[(c*32+bh)*2048 + d*64 + vd], dvec[(c*32+bh)*32 + d] = exp(b_last)
// LDS layout (41 KB -> 3 blocks/CU):
//   [0,8K)   sq  (dies after QK^T)     \__ sA (64x64 f32, XOR-swizzled)
//   [8K,16K) sb  (dies after pass 2)   /   overlays after a barrier
//   [16K,24K) sk (ke2)
//   [24K,40K) sv
//   [40K,..) ebl[32]

__global__ __launch_bounds__(256) void k_phase1(unsigned short* __restrict__ pbuf,
                                                const float* __restrict__ gkbuf,
                                                float* __restrict__ obuf,
                                                float* __restrict__ U,
                                                float* __restrict__ dvec) {
  const int bi = blockIdx.x;
  const int c = bi >> 5, bh = bi & 31;
  const int b = bh >> 4, h = bh & 15;
  const int tid = threadIdx.x;

  __shared__ __align__(16) char smem[41088];
  float* sq  = (float*)smem;              // 64*32
  float* sb  = (float*)(smem + 8192);     // 64*32
  float* sAm = (float*)smem;              // 64*64 swizzled (overlay)
  float* sk  = (float*)(smem + 16384);    // 64*32
  float* sv  = (float*)(smem + 24576);    // 64*64
  float* ebl = (float*)(smem + 40960);    // 32

  const size_t rq = (size_t)(b * T_ + c * 64) * NF_ + Q0_ + h * 32;
  const size_t rk = (size_t)(b * T_ + c * 64) * NF_ + K0_ + h * 32;
  const size_t rg = (size_t)(b * T_ + c * 64) * KD_ + h * 32;
  const size_t rv = (size_t)(b * T_ + c * 64) * NF_ + V0_ + h * 64;

#pragma unroll
  for (int s = 0; s < 8; ++s) {
    int e = tid + s * 256;
    int i = e >> 5, d = e & 31;
    sq[e] = bf2f(pbuf[rq + (size_t)i * NF_ + d]);
    sk[e] = bf2f(pbuf[rk + (size_t)i * NF_ + d]);
    sb[e] = gkbuf[rg + (size_t)i * KD_ + d];
  }
#pragma unroll
  for (int s = 0; s < 16; ++s) {
    int e = tid + s * 256;
    int i = e >> 6, vd = e & 63;
    sv[e] = bf2f(pbuf[rv + (size_t)i * NF_ + vd]);
  }
  __syncthreads();

  if (tid < 32) {
    float run = 0.0f;
    for (int i = 0; i < 64; ++i) { run += sb[i * 32 + tid]; sb[i * 32 + tid] = run; }
    float e = __expf(run);
    ebl[tid] = e;
    dvec[((size_t)c * 32 + bh) * 32 + tid] = e;
  }
  __syncthreads();

#pragma unroll
  for (int s = 0; s < 8; ++s) {
    int e = tid + s * 256;
    int i = e >> 5, d = e & 31;
    float bb = sb[e];
    float qe = sq[e] * __expf(bb) * SCALE_;
    sq[e] = qe;
    pbuf[rq + (size_t)i * NF_ + d] = f2bf(qe);
    sk[e] = sk[e] * __expf(-bb);   // ke2
  }
  __syncthreads();

  // A = qe @ ke2^T, masked lower-tri; staggered d => <=2-way bank aliasing
  const int ti = tid >> 4, tj = tid & 15;
  const int i0 = ti * 4, j0 = tj * 4;
  {
    float a[4][4] = {};
    if (j0 <= i0 + 3) {
      for (int dd = 0; dd < 32; ++dd) {
        int d = (dd + tid) & 31;
        float qv[4], kv[4];
#pragma unroll
        for (int x = 0; x < 4; ++x) qv[x] = sq[(i0 + x) * 32 + d];
#pragma unroll
        for (int y = 0; y < 4; ++y) kv[y] = sk[(j0 + y) * 32 + d];
#pragma unroll
        for (int x = 0; x < 4; ++x)
#pragma unroll
          for (int y = 0; y < 4; ++y) a[x][y] += qv[x] * kv[y];
      }
    }
    __syncthreads();   // sq/sb fully consumed; safe to overlay sA
#pragma unroll
    for (int x = 0; x < 4; ++x) {
      int r = i0 + x, sw = r & 31;
#pragma unroll
      for (int y = 0; y < 4; ++y)
        sAm[r * 64 + ((j0 + y) ^ sw)] = (j0 + y <= r) ? a[x][y] : 0.0f;
    }
  }
  __syncthreads();

  // o_intra = A @ v -> obuf
  {
    const int v0 = tj * 4;
    float o[4][4] = {};
    for (int j = 0; j <= i0 + 3; ++j) {
      float av[4], vv[4];
#pragma unroll
      for (int x = 0; x < 4; ++x) { int r = i0 + x; av[x] = sAm[r * 64 + (j ^ (r & 31))]; }
#pragma unroll
      for (int y = 0; y < 4; ++y) vv[y] = sv[j * 64 + v0 + y];
#pragma unroll
      for (int x = 0; x < 4; ++x)
#pragma unroll
        for (int y = 0; y < 4; ++y) o[x][y] += av[x] * vv[y];
    }
    size_t ob = ((size_t)c * 32 + bh) * 4096;
#pragma unroll
    for (int x = 0; x < 4; ++x) {
      float4 f4 = make_float4(o[x][0], o[x][1], o[x][2], o[x][3]);
      *(float4*)(obuf + ob + (size_t)(i0 + x) * 64 + v0) = f4;
    }
  }

  // U[d][vd] = ebl[d] * sum_i ke2[i][d] * v[i][vd]
  {
    const int d0 = ti * 2, v0 = tj * 4;
    float u[2][4] = {};
    for (int i = 0; i < 64; ++i) {
      float kv[2], vv[4];
#pragma unroll
      for (int x = 0; x < 2; ++x) kv[x] = sk[i * 32 + d0 + x];
#pragma unroll
      for (int y = 0; y < 4; ++y) vv[y] = sv[i * 64 + v0 + y];
#pragma unroll
      for (int x = 0; x < 2; ++x)
#pragma unroll
        for (int y = 0; y < 4; ++y) u[x][y] += kv[x] * vv[y];
    }
    size_t ub = ((size_t)c * 32 + bh) * 2048;
#pragma unroll
    for (int x = 0; x < 2; ++x) {
      float e = ebl[d0 + x];
      float4 f4 = make_float4(u[x][0] * e, u[x][1] * e, u[x][2] * e, u[x][3] * e);
      *(float4*)(U + ub + (size_t)(d0 + x) * 64 + v0) = f4;
    }
  }
}

// ---------------- phase 2: inter-chunk state recurrence ----------------

__global__ __launch_bounds__(256) void k_phase2(const float* __restrict__ U,
                                                const float* __restrict__ dvec,
                                                float* __restrict__ S) {
  int idx = blockIdx.x * 256 + threadIdx.x;   // B*H*HK*HV = 65536
  int bh = idx >> 11, r = idx & 2047;
  int d = r >> 6;
  float run = 0.0f;
  for (int c = 0; c < NC_; ++c) {
    size_t o = ((size_t)c * 32 + bh) * 2048 + r;
    S[o] = run;
    run = dvec[((size_t)c * 32 + bh) * 32 + d] * run + U[o];
  }
}

// ---------------- phase 3 fused with RMS/swish gate ----------------
// o_final = o_intra + qe @ S_c ; y = rms(o)*nw * g*sigmoid(g)  (bf16)

__global__ __launch_bounds__(256) void k_phase3rms(const unsigned short* __restrict__ pbuf,
                                                   const float* __restrict__ obuf,
                                                   const float* __restrict__ S,
                                                   const float* __restrict__ norm_w,
                                                   unsigned short* __restrict__ ybuf) {
  const int bi = blockIdx.x;
  const int c = bi >> 5, bh = bi & 31;
  const int b = bh >> 4, h = bh & 15;
  const int tid = threadIdx.x;
  __shared__ float sq[64 * 32];
  __shared__ float sS[32 * 64];
  __shared__ float sO[64 * 65];
  const size_t rq = (size_t)(b * T_ + c * 64) * NF_ + Q0_ + h * 32;
  const size_t sbase = ((size_t)c * 32 + bh) * 2048;
  const size_t ob = ((size_t)c * 32 + bh) * 4096;

#pragma unroll
  for (int s = 0; s < 8; ++s) {
    int e = tid + s * 256;
    int i = e >> 5, d = e & 31;
    sq[e] = bf2f(pbuf[rq + (size_t)i * NF_ + d]);
    sS[e] = S[sbase + e];
  }
  __syncthreads();

  const int ti = tid >> 4, tv = tid & 15;
  const int i0 = ti * 4, v0 = tv * 4;
  float acc[4][4] = {};
  for (int dd = 0; dd < 32; ++dd) {
    int d = (dd + tid) & 31;
    float qv[4], sv4[4];
#pragma unroll
    for (int x = 0; x < 4; ++x) qv[x] = sq[(i0 + x) * 32 + d];
#pragma unroll
    for (int y = 0; y < 4; ++y) sv4[y] = sS[d * 64 + v0 + y];
#pragma unroll
    for (int x = 0; x < 4; ++x)
#pragma unroll
      for (int y = 0; y < 4; ++y) acc[x][y] += qv[x] * sv4[y];
  }
#pragma unroll
  for (int x = 0; x < 4; ++x) {
    float4 oi = *(const float4*)(obuf + ob + (size_t)(i0 + x) * 64 + v0);
    sO[(i0 + x) * 65 + v0 + 0] = acc[x][0] + oi.x;
    sO[(i0 + x) * 65 + v0 + 1] = acc[x][1] + oi.y;
    sO[(i0 + x) * 65 + v0 + 2] = acc[x][2] + oi.z;
    sO[(i0 + x) * 65 + v0 + 3] = acc[x][3] + oi.w;
  }
  __syncthreads();

  // RMS + swish: 4 waves x 16 rows, lane = vd
  const int wave = tid >> 6, lane = tid & 63;
  const float nwv = norm_w[lane];
#pragma unroll
  for (int it = 0; it < 16; ++it) {
    int row = wave * 16 + it;
    float ov = sO[row * 65 + lane];
    float s = ov * ov;
#pragma unroll
    for (int d = 32; d; d >>= 1) s += __shfl_xor(s, d, 64);
    float rs = rsqrtf(s * (1.0f / 64.0f) + EPS_);
    int m = b * T_ + c * 64 + row;
    float gv = bf2f(pbuf[(size_t)m * NF_ + G0_ + h * 64 + lane]);
    float sw = gv / (1.0f + __expf(-gv));
    ybuf[(size_t)m * VD_ + h * 64 + lane] = f2bf(ov * rs * nwv * sw);
  }
}

// ---------------- launch ----------------

extern "C" void kernel_launch(void* const* d_in, const int* in_sizes, int n_in,
                              void* d_out, int out_size, void* d_ws, size_t ws_size,
                              hipStream_t stream) {
  const float* x    = (const float*)d_in[0];
  const float* Wq   = (const float*)d_in[1];
  const float* Wk   = (const float*)d_in[2];
  const float* Wv   = (const float*)d_in[3];
  const float* Wgk1 = (const float*)d_in[4];
  const float* Wgk2 = (const float*)d_in[5];
  const float* bgk  = (const float*)d_in[6];
  const float* Wg   = (const float*)d_in[7];
  const float* nw   = (const float*)d_in[8];
  const float* Wo   = (const float*)d_in[9];
  float* out = (float*)d_out;

  char* p = (char*)d_ws;
  unsigned short* xb   = (unsigned short*)p;  p += (size_t)M_ * D_ * 2;
  unsigned short* Wcat = (unsigned short*)p;  p += (size_t)NF_ * D_ * 2;
  unsigned short* woT  = (unsigned short*)p;  p += (size_t)D_ * VD_ * 2;
  unsigned short* pbuf = (unsigned short*)p;  p += (size_t)M_ * NF_ * 2;
  float* gkbuf = (float*)p;  p += (size_t)M_ * KD_ * 4;
  float* obuf  = (float*)p;  p += (size_t)M_ * VD_ * 4;
  float* Ubuf  = (float*)p;  p += (size_t)NC_ * 32 * 2048 * 4;
  float* Sbuf  = (float*)p;  p += (size_t)NC_ * 32 * 2048 * 4;
  float* dbuf  = (float*)p;  p += (size_t)NC_ * 32 * 32 * 4;
  unsigned short* ybuf = (unsigned short*)p;  p += (size_t)M_ * VD_ * 2;

  // conversions
  k_f32_to_bf16<<<(M_ * D_ / 4) / 256, 256, 0, stream>>>(x, xb, M_ * D_);
  k_transpose_all<<<dim3(32, 32, 5), 256, 0, stream>>>(Wq, Wk, Wv, Wg, Wo, Wcat, woT);
  k_pad_wgk1<<<(128 * D_) / 256, 256, 0, stream>>>(Wgk1, Wcat + (size_t)GL0_ * D_);

  // fused projections: q|k|v|g|glow in one GEMM, bf16 out
  k_gemm_bt<unsigned short><<<dim3(NF_/128, M_/128), 256, 0, stream>>>(xb, Wcat, pbuf, M_, NF_, D_);

  // gate nonlinearity
  k_gate<<<(M_ * KD_) / 256, 256, 0, stream>>>(pbuf, Wgk2, bgk, gkbuf);

  // attention
  k_phase1<<<NC_ * 32, 256, 0, stream>>>(pbuf, gkbuf, obuf, Ubuf, dbuf);
  k_phase2<<<(32 * 2048) / 256, 256, 0, stream>>>(Ubuf, dbuf, Sbuf);
  k_phase3rms<<<NC_ * 32, 256, 0, stream>>>(pbuf, obuf, Sbuf, nw, ybuf);

  // output projection (f32 out)
  k_gemm_bt<float><<<dim3(D_/128, M_/128), 256, 0, stream>>>(ybuf, woT, out, M_, D_, VD_);
}

// Round 4
// 312.105 us; speedup vs baseline: 2.0637x; 1.0435x over previous
//
#include <hip/hip_runtime.h>
#include <cstddef>

#define B_   2
#define T_   4096
#define D_   1024
#define H_   16
#define KD_  512
#define VD_  1024
#define HK_  32
#define HV_  64
#define NC_  64          // T/CHUNK
#define M_   (B_*T_)     // 8192
#define GR_  16
#define EPS_ 1e-5f
#define SCALE_ 0.17677669529663687f  // 32^-0.5
#define GNORM_INV_ (1.0f/16.0f)

// fused projection layout: cols [0,512)=q, [512,1024)=k, [1024,2048)=v,
// [2048,3072)=g, [3072,3200)=glow (only first 16 weight rows nonzero)
#define NF_   3200
#define Q0_   0
#define K0_   512
#define V0_   1024
#define G0_   2048
#define GL0_  3072

typedef __attribute__((ext_vector_type(8))) __bf16 bf16x8;
typedef __attribute__((ext_vector_type(4))) float f32x4;

__device__ inline unsigned short f2bf(float f) {
  unsigned int u = __float_as_uint(f);
  u = (u + 0x7fffu + ((u >> 16) & 1u)) >> 16;
  return (unsigned short)u;
}
__device__ inline float bf2f(unsigned short u) {
  return __uint_as_float((unsigned int)u << 16);
}
__device__ inline void unpack8(uint4 u, float* f) {
  f[0] = bf2f(u.x & 0xffff); f[1] = bf2f(u.x >> 16);
  f[2] = bf2f(u.y & 0xffff); f[3] = bf2f(u.y >> 16);
  f[4] = bf2f(u.z & 0xffff); f[5] = bf2f(u.z >> 16);
  f[6] = bf2f(u.w & 0xffff); f[7] = bf2f(u.w >> 16);
}

__device__ __forceinline__ void gload_lds16(const unsigned short* g, unsigned short* l) {
  __builtin_amdgcn_global_load_lds(
      (const __attribute__((address_space(1))) unsigned int*)g,
      (__attribute__((address_space(3))) unsigned int*)l, 16, 0, 0);
}

// ---------------- elementwise conversions ----------------

__global__ __launch_bounds__(256) void k_f32_to_bf16(const float* __restrict__ in,
                                                     unsigned short* __restrict__ out, int n4) {
  int i = (blockIdx.x * 256 + threadIdx.x) * 4;
  float4 f = *(const float4*)(in + i);
  ushort4 o;
  o.x = f2bf(f.x); o.y = f2bf(f.y); o.z = f2bf(f.z); o.w = f2bf(f.w);
  *(ushort4*)(out + i) = o;
}

// all weight transposes (+Wgk1 pad) in one launch. z selects the matrix.
__global__ __launch_bounds__(256) void k_transpose_all(const float* __restrict__ Wq,
                                                       const float* __restrict__ Wk,
                                                       const float* __restrict__ Wv,
                                                       const float* __restrict__ Wg,
                                                       const float* __restrict__ Wo,
                                                       const float* __restrict__ Wgk1,
                                                       unsigned short* __restrict__ Wcat,
                                                       unsigned short* __restrict__ woT) {
  __shared__ float tile[32][33];
  const float* in; unsigned short* out; int N;
  switch (blockIdx.z) {
    case 0: in = Wq;   out = Wcat + (size_t)Q0_ * D_;  N = 512;  break;
    case 1: in = Wk;   out = Wcat + (size_t)K0_ * D_;  N = 512;  break;
    case 2: in = Wv;   out = Wcat + (size_t)V0_ * D_;  N = 1024; break;
    case 3: in = Wg;   out = Wcat + (size_t)G0_ * D_;  N = 1024; break;
    case 4: in = Wo;   out = woT;                      N = 1024; break;
    default: in = Wgk1; out = Wcat + (size_t)GL0_ * D_; N = 128;  break;  // pad: cols >= 16 are 0
  }
  int n0 = blockIdx.x * 32, k0 = blockIdx.y * 32;
  if (n0 >= N) return;
  int tx = threadIdx.x & 31, ty = threadIdx.x >> 5;   // 32 x 8
  if (blockIdx.z == 5) {
#pragma unroll
    for (int p = 0; p < 4; ++p)
      tile[ty + p*8][tx] = (n0 + tx < GR_) ? in[(size_t)(k0 + ty + p*8) * GR_ + n0 + tx] : 0.0f;
  } else {
#pragma unroll
    for (int p = 0; p < 4; ++p)
      tile[ty + p*8][tx] = in[(size_t)(k0 + ty + p*8) * N + n0 + tx];
  }
  __syncthreads();
#pragma unroll
  for (int p = 0; p < 4; ++p)
    out[(size_t)(n0 + ty + p*8) * 1024 + k0 + tx] = f2bf(tile[tx][ty + p*8]);
}

// ---------------- bf16 MFMA GEMM: C(MxN) = A(MxK) * Bt(NxK)^T ----------------
// 128x128 tile, BK=64, 256 threads (4 waves 2x2), 16x16x32 MFMA.
// 1D grid with XCD-aware swizzle: xcd = g&7 owns 8 contiguous M-tiles for all
// N-tiles -> A working set (2 MB) stays resident in that XCD's 4 MB L2.
// Requires M == 8192 (64 M-tiles = 8 per XCD).

template <typename OutT>
__global__ __launch_bounds__(256) void k_gemm_bt(const unsigned short* __restrict__ A,
                                                 const unsigned short* __restrict__ Bt,
                                                 OutT* __restrict__ C,
                                                 int M, int N, int K) {
  __shared__ __align__(16) unsigned short sA[128 * 64];
  __shared__ __align__(16) unsigned short sB[128 * 64];
  const int tid  = threadIdx.x;
  const int lane = tid & 63;
  const int wave = tid >> 6;
  const int wr = wave >> 1, wc = wave & 1;
  const int quad = lane >> 4, l16 = lane & 15;

  const int g = blockIdx.x;
  const int xcd = g & 7, slot = g >> 3;
  const int bm0 = ((xcd << 3) | (slot & 7)) << 7;   // M-tile
  const int bn0 = (slot >> 3) << 7;                 // N-tile

  const int lrow = lane >> 3;                      // 0..7 (== row & 7)
  const int gcol = ((lane & 7) ^ lrow) * 8;        // swizzled source column
  const unsigned short* ga = A  + (size_t)(bm0 + wave * 8 + lrow) * K + gcol;
  const unsigned short* gb = Bt + (size_t)(bn0 + wave * 8 + lrow) * K + gcol;
  unsigned short* la = sA + wave * 8 * 64;
  unsigned short* lb = sB + wave * 8 * 64;

  f32x4 acc[4][4] = {};

  for (int k0 = 0; k0 < K; k0 += 64) {
#pragma unroll
    for (int it = 0; it < 4; ++it) {
      gload_lds16(ga + k0 + (size_t)it * 32 * K, la + it * 32 * 64);
      gload_lds16(gb + k0 + (size_t)it * 32 * K, lb + it * 32 * 64);
    }
    __syncthreads();
#pragma unroll
    for (int kk = 0; kk < 2; ++kk) {
      bf16x8 af[4], bfv[4];
#pragma unroll
      for (int i = 0; i < 4; ++i) {
        int row = wr * 64 + i * 16 + l16;
        int gg = (kk * 4 + quad) ^ (row & 7);
        af[i] = *(const bf16x8*)(sA + row * 64 + gg * 8);
      }
#pragma unroll
      for (int j = 0; j < 4; ++j) {
        int row = wc * 64 + j * 16 + l16;
        int gg = (kk * 4 + quad) ^ (row & 7);
        bfv[j] = *(const bf16x8*)(sB + row * 64 + gg * 8);
      }
#pragma unroll
      for (int i = 0; i < 4; ++i)
#pragma unroll
        for (int j = 0; j < 4; ++j)
          acc[i][j] = __builtin_amdgcn_mfma_f32_16x16x32_bf16(af[i], bfv[j], acc[i][j], 0, 0, 0);
    }
    __syncthreads();
  }

#pragma unroll
  for (int i = 0; i < 4; ++i) {
    int row0 = bm0 + wr * 64 + i * 16 + quad * 4;
#pragma unroll
    for (int j = 0; j < 4; ++j) {
      int col = bn0 + wc * 64 + j * 16 + l16;
#pragma unroll
      for (int r = 0; r < 4; ++r) {
        float v = acc[i][j][r];
        if constexpr (sizeof(OutT) == 2)
          C[(size_t)(row0 + r) * N + col] = (OutT)f2bf(v);
        else
          C[(size_t)(row0 + r) * N + col] = (OutT)v;
      }
    }
  }
}

// ---------------- phase 1: gate MLP + cumsum + intra-chunk attention ----------------
// One block per (chunk, b, h). Computes gk slice inline (glow @ Wgk2 + bgk ->
// logsigmoid/16), cumsum via wave-scan, qe/ke2, masked QK^T, A@V -> obuf(bf16),
// U(bf16), dvec(f32). qe written back to pbuf (bf16) for phase3.
// LDS layouts (bank-audited): sq_t/sb_t transposed stride-65, sk stride-33,
// sv stride-65, sAm stride-64 XOR-swizzled overlay on sq_t+sb_t.

__global__ __launch_bounds__(256) void k_phase1(unsigned short* __restrict__ pbuf,
                                                const float* __restrict__ Wgk2,
                                                const float* __restrict__ bgk,
                                                unsigned short* __restrict__ obuf,
                                                unsigned short* __restrict__ U,
                                                float* __restrict__ dvec) {
  const int bi = blockIdx.x;
  const int c = bi >> 5, bh = bi & 31;
  const int b = bh >> 4, h = bh & 15;
  const int tid = threadIdx.x;
  const int lane = tid & 63, wave = tid >> 6;

  __shared__ __align__(16) char smem[48384];
  float* sq_t  = (float*)smem;                 // 32 x 65 (d-major)  [0,8320)
  float* sb_t  = (float*)(smem + 8320);        // 32 x 65 (d-major)  [8320,16640)
  float* sAm   = (float*)smem;                 // 64 x 64 XOR-swizzled overlay
  float* sk    = (float*)(smem + 16640);       // 64 x 33
  float* sv    = (float*)(smem + 25088);       // 64 x 65
  float* sglow = (float*)(smem + 41728);       // 64 x 17
  float* sw2   = (float*)(smem + 46080);       // 16 x 32
  float* sbgk  = (float*)(smem + 48128);       // 32
  float* ebl   = (float*)(smem + 48256);       // 32

  const size_t row0 = (size_t)(b * T_ + c * 64);
  const size_t rq  = row0 * NF_ + Q0_ + h * 32;
  const size_t rk  = row0 * NF_ + K0_ + h * 32;
  const size_t rv  = row0 * NF_ + V0_ + h * 64;
  const size_t rgl = row0 * NF_ + GL0_;

  // ---- global loads (vectorized) ----
  const int qr = tid >> 2, qs = tid & 3;           // q/k: row 0..63, seg 0..3
  uint4 qu = *(const uint4*)(pbuf + rq + (size_t)qr * NF_ + qs * 8);
  uint4 ku = *(const uint4*)(pbuf + rk + (size_t)qr * NF_ + qs * 8);
  uint4 vu[2];
#pragma unroll
  for (int s = 0; s < 2; ++s) {
    int e = tid + s * 256;
    vu[s] = *(const uint4*)(pbuf + rv + (size_t)(e >> 3) * NF_ + (e & 7) * 8);
  }
  uint4 gl = {};
  float4 w2v = {};
  if (tid < 128) {
    gl  = *(const uint4*)(pbuf + rgl + (size_t)(tid >> 1) * NF_ + (tid & 1) * 8);
    w2v = *(const float4*)(Wgk2 + (tid >> 3) * KD_ + h * 32 + (tid & 7) * 4);
  }
  if (tid < 8) *(float4*)(sbgk + tid * 4) = *(const float4*)(bgk + h * 32 + tid * 4);

  // LDS stores
#pragma unroll
  for (int s = 0; s < 2; ++s) {
    int e = tid + s * 256;
    int r = e >> 3, seg = e & 7;
    float f[8]; unpack8(vu[s], f);
#pragma unroll
    for (int j = 0; j < 8; ++j) sv[r * 65 + seg * 8 + j] = f[j];
  }
  if (tid < 128) {
    int r = tid >> 1, seg = tid & 1;
    float f[8]; unpack8(gl, f);
#pragma unroll
    for (int j = 0; j < 8; ++j) sglow[r * 17 + seg * 8 + j] = f[j];
    *(float4*)(sw2 + (tid >> 3) * 32 + (tid & 7) * 4) = w2v;
  }
  __syncthreads();

  // ---- gate MLP: sb_t[d][i] = logsigmoid(glow[i] . w2[:,d] + bgk[d]) / 16 ----
#pragma unroll
  for (int s = 0; s < 8; ++s) {
    int e = tid + s * 256;
    int i = e & 63, d = e >> 6;       // d wave-uniform
    float acc = sbgk[d];
#pragma unroll
    for (int r = 0; r < GR_; ++r) acc += sglow[i * 17 + r] * sw2[r * 32 + d];
    float ls = fminf(acc, 0.0f) - __logf(1.0f + __expf(-fabsf(acc)));
    sb_t[d * 65 + i] = ls * GNORM_INV_;
  }
  __syncthreads();

  // ---- cumsum over i (wave-parallel scan, 8 columns per wave) ----
#pragma unroll
  for (int j = 0; j < 8; ++j) {
    int d = wave * 8 + j;
    float v = sb_t[d * 65 + lane];
#pragma unroll
    for (int off = 1; off < 64; off <<= 1) {
      int src = lane - off;
      float t = __shfl(v, src < 0 ? 0 : src, 64);
      if (lane >= off) v += t;
    }
    sb_t[d * 65 + lane] = v;
    if (lane == 63) {
      float e = __expf(v);
      ebl[d] = e;
      dvec[((size_t)c * 32 + bh) * 32 + d] = e;
    }
  }
  __syncthreads();

  // ---- qe = q*exp(b)*scale (-> sq_t + pbuf), ke2 = k*exp(-b) (-> sk) ----
  {
    float qf[8], kf[8]; unpack8(qu, qf); unpack8(ku, kf);
    unsigned short qo[8];
#pragma unroll
    for (int j = 0; j < 8; ++j) {
      int d = qs * 8 + j;
      float bb = sb_t[d * 65 + qr];
      float qe = qf[j] * __expf(bb) * SCALE_;
      float ke = kf[j] * __expf(-bb);
      sq_t[d * 65 + qr] = qe;
      sk[qr * 33 + d] = ke;
      qo[j] = f2bf(qe);
    }
    uint4 qw;
    qw.x = (unsigned int)qo[0] | ((unsigned int)qo[1] << 16);
    qw.y = (unsigned int)qo[2] | ((unsigned int)qo[3] << 16);
    qw.z = (unsigned int)qo[4] | ((unsigned int)qo[5] << 16);
    qw.w = (unsigned int)qo[6] | ((unsigned int)qo[7] << 16);
    *(uint4*)(pbuf + rq + (size_t)qr * NF_ + qs * 8) = qw;
  }
  __syncthreads();

  // ---- A = qe @ ke2^T, masked lower-tri ----
  const int ti = tid >> 4, tj = tid & 15;
  const int i0 = ti * 4, j0 = tj * 4;
  {
    float a[4][4] = {};
    if (j0 <= i0 + 3) {
      for (int dd = 0; dd < 32; ++dd) {
        int d = (dd + tid) & 31;
        float qv[4], kv[4];
#pragma unroll
        for (int x = 0; x < 4; ++x) qv[x] = sq_t[d * 65 + i0 + x];
#pragma unroll
        for (int y = 0; y < 4; ++y) kv[y] = sk[(j0 + y) * 33 + d];
#pragma unroll
        for (int x = 0; x < 4; ++x)
#pragma unroll
          for (int y = 0; y < 4; ++y) a[x][y] += qv[x] * kv[y];
      }
    }
    __syncthreads();   // sq_t/sb_t fully consumed; overlay sAm
#pragma unroll
    for (int x = 0; x < 4; ++x) {
      int r = i0 + x, sw = r & 31;
#pragma unroll
      for (int y = 0; y < 4; ++y)
        sAm[r * 64 + ((j0 + y) ^ sw)] = (j0 + y <= r) ? a[x][y] : 0.0f;
    }
  }
  __syncthreads();

  // ---- o_intra = A @ v -> obuf (bf16) ----
  {
    const int v0 = tj * 4;
    float o[4][4] = {};
    for (int j = 0; j <= i0 + 3; ++j) {
      float av[4], vv[4];
#pragma unroll
      for (int x = 0; x < 4; ++x) { int r = i0 + x; av[x] = sAm[r * 64 + (j ^ (r & 31))]; }
#pragma unroll
      for (int y = 0; y < 4; ++y) vv[y] = sv[j * 65 + v0 + y];
#pragma unroll
      for (int x = 0; x < 4; ++x)
#pragma unroll
        for (int y = 0; y < 4; ++y) o[x][y] += av[x] * vv[y];
    }
    size_t ob = ((size_t)c * 32 + bh) * 4096;
#pragma unroll
    for (int x = 0; x < 4; ++x) {
      ushort4 u = { f2bf(o[x][0]), f2bf(o[x][1]), f2bf(o[x][2]), f2bf(o[x][3]) };
      *(ushort4*)(obuf + ob + (size_t)(i0 + x) * 64 + v0) = u;
    }
  }

  // ---- U[d][vd] = ebl[d] * sum_i ke2[i][d]*v[i][vd] -> bf16 ----
  {
    const int d0 = ti * 2, v0 = tj * 4;
    float u[2][4] = {};
    for (int i = 0; i < 64; ++i) {
      float kv[2], vv[4];
#pragma unroll
      for (int x = 0; x < 2; ++x) kv[x] = sk[i * 33 + d0 + x];
#pragma unroll
      for (int y = 0; y < 4; ++y) vv[y] = sv[i * 65 + v0 + y];
#pragma unroll
      for (int x = 0; x < 2; ++x)
#pragma unroll
        for (int y = 0; y < 4; ++y) u[x][y] += kv[x] * vv[y];
    }
    size_t ub = ((size_t)c * 32 + bh) * 2048;
#pragma unroll
    for (int x = 0; x < 2; ++x) {
      float e = ebl[d0 + x];
      ushort4 uu = { f2bf(u[x][0] * e), f2bf(u[x][1] * e), f2bf(u[x][2] * e), f2bf(u[x][3] * e) };
      *(ushort4*)(U + ub + (size_t)(d0 + x) * 64 + v0) = uu;
    }
  }
}

// ---------------- phase 2: inter-chunk state recurrence (bf16 U/S) ----------------

__global__ __launch_bounds__(256) void k_phase2(const unsigned short* __restrict__ U,
                                                const float* __restrict__ dvec,
                                                unsigned short* __restrict__ S) {
  int idx = blockIdx.x * 256 + threadIdx.x;       // 32768 threads, 2 elems each
  int bh = idx >> 10, r2 = (idx & 1023) << 1;
  int d = r2 >> 6;
  float run0 = 0.0f, run1 = 0.0f;
  for (int c = 0; c < NC_; ++c) {
    size_t o = ((size_t)c * 32 + bh) * 2048 + r2;
    unsigned int uu = *(const unsigned int*)(U + o);
    *(unsigned int*)(S + o) =
        (unsigned int)f2bf(run0) | ((unsigned int)f2bf(run1) << 16);
    float dv = dvec[((size_t)c * 32 + bh) * 32 + d];
    run0 = dv * run0 + bf2f(uu & 0xffff);
    run1 = dv * run1 + bf2f(uu >> 16);
  }
}

// ---------------- phase 3 fused with RMS/swish gate ----------------

__global__ __launch_bounds__(256) void k_phase3rms(const unsigned short* __restrict__ pbuf,
                                                   const unsigned short* __restrict__ obuf,
                                                   const unsigned short* __restrict__ S,
                                                   const float* __restrict__ norm_w,
                                                   unsigned short* __restrict__ ybuf) {
  const int bi = blockIdx.x;
  const int c = bi >> 5, bh = bi & 31;
  const int b = bh >> 4, h = bh & 15;
  const int tid = threadIdx.x;

  __shared__ __align__(16) char smem[33280 + 16640];
  float* sq_t = (float*)smem;                 // 32 x 65 (d-major)
  float* sS   = (float*)(smem + 8320);        // 32 x 65
  float* sO   = (float*)(smem + 16640);       // 64 x 65

  const size_t rq = (size_t)(b * T_ + c * 64) * NF_ + Q0_ + h * 32;
  const size_t sbase = ((size_t)c * 32 + bh) * 2048;
  const size_t ob = ((size_t)c * 32 + bh) * 4096;

  {
    int r = tid >> 2, seg = tid & 3;
    uint4 qu = *(const uint4*)(pbuf + rq + (size_t)r * NF_ + seg * 8);
    float f[8]; unpack8(qu, f);
#pragma unroll
    for (int j = 0; j < 8; ++j) sq_t[(seg * 8 + j) * 65 + r] = f[j];
    int d = tid >> 3, seg2 = tid & 7;
    uint4 su = *(const uint4*)(S + sbase + (size_t)d * 64 + seg2 * 8);
    float g[8]; unpack8(su, g);
#pragma unroll
    for (int j = 0; j < 8; ++j) sS[d * 65 + seg2 * 8 + j] = g[j];
  }
  __syncthreads();

  const int ti = tid >> 4, tv = tid & 15;
  const int i0 = ti * 4, v0 = tv * 4;
  float acc[4][4] = {};
  for (int dd = 0; dd < 32; ++dd) {
    int d = (dd + tid) & 31;
    float qv[4], sv4[4];
#pragma unroll
    for (int x = 0; x < 4; ++x) qv[x] = sq_t[d * 65 + i0 + x];
#pragma unroll
    for (int y = 0; y < 4; ++y) sv4[y] = sS[d * 65 + v0 + y];
#pragma unroll
    for (int x = 0; x < 4; ++x)
#pragma unroll
      for (int y = 0; y < 4; ++y) acc[x][y] += qv[x] * sv4[y];
  }
#pragma unroll
  for (int x = 0; x < 4; ++x) {
    ushort4 oi = *(const ushort4*)(obuf + ob + (size_t)(i0 + x) * 64 + v0);
    sO[(i0 + x) * 65 + v0 + 0] = acc[x][0] + bf2f(oi.x);
    sO[(i0 + x) * 65 + v0 + 1] = acc[x][1] + bf2f(oi.y);
    sO[(i0 + x) * 65 + v0 + 2] = acc[x][2] + bf2f(oi.z);
    sO[(i0 + x) * 65 + v0 + 3] = acc[x][3] + bf2f(oi.w);
  }
  __syncthreads();

  // RMS + swish: 4 waves x 16 rows, lane = vd
  const int wave = tid >> 6, lane = tid & 63;
  const float nwv = norm_w[lane];
#pragma unroll
  for (int it = 0; it < 16; ++it) {
    int row = wave * 16 + it;
    float ov = sO[row * 65 + lane];
    float s = ov * ov;
#pragma unroll
    for (int d = 32; d; d >>= 1) s += __shfl_xor(s, d, 64);
    float rs = rsqrtf(s * (1.0f / 64.0f) + EPS_);
    int m = b * T_ + c * 64 + row;
    float gv = bf2f(pbuf[(size_t)m * NF_ + G0_ + h * 64 + lane]);
    float sw = gv / (1.0f + __expf(-gv));
    ybuf[(size_t)m * VD_ + h * 64 + lane] = f2bf(ov * rs * nwv * sw);
  }
}

// ---------------- launch ----------------

extern "C" void kernel_launch(void* const* d_in, const int* in_sizes, int n_in,
                              void* d_out, int out_size, void* d_ws, size_t ws_size,
                              hipStream_t stream) {
  const float* x    = (const float*)d_in[0];
  const float* Wq   = (const float*)d_in[1];
  const float* Wk   = (const float*)d_in[2];
  const float* Wv   = (const float*)d_in[3];
  const float* Wgk1 = (const float*)d_in[4];
  const float* Wgk2 = (const float*)d_in[5];
  const float* bgk  = (const float*)d_in[6];
  const float* Wg   = (const float*)d_in[7];
  const float* nw   = (const float*)d_in[8];
  const float* Wo   = (const float*)d_in[9];
  float* out = (float*)d_out;

  char* p = (char*)d_ws;
  unsigned short* xb   = (unsigned short*)p;  p += (size_t)M_ * D_ * 2;
  unsigned short* Wcat = (unsigned short*)p;  p += (size_t)NF_ * D_ * 2;
  unsigned short* woT  = (unsigned short*)p;  p += (size_t)D_ * VD_ * 2;
  unsigned short* pbuf = (unsigned short*)p;  p += (size_t)M_ * NF_ * 2;
  unsigned short* obuf = (unsigned short*)p;  p += (size_t)M_ * VD_ * 2;
  unsigned short* Ubuf = (unsigned short*)p;  p += (size_t)NC_ * 32 * 2048 * 2;
  unsigned short* Sbuf = (unsigned short*)p;  p += (size_t)NC_ * 32 * 2048 * 2;
  float* dbuf = (float*)p;                    p += (size_t)NC_ * 32 * 32 * 4;
  unsigned short* ybuf = (unsigned short*)p;  p += (size_t)M_ * VD_ * 2;

  // conversions
  k_f32_to_bf16<<<(M_ * D_ / 4) / 256, 256, 0, stream>>>(x, xb, M_ * D_);
  k_transpose_all<<<dim3(32, 32, 6), 256, 0, stream>>>(Wq, Wk, Wv, Wg, Wo, Wgk1, Wcat, woT);

  // fused projections: q|k|v|g|glow in one GEMM (bf16 out), XCD-swizzled
  k_gemm_bt<unsigned short><<<(NF_/128) * (M_/128), 256, 0, stream>>>(xb, Wcat, pbuf, M_, NF_, D_);

  // attention (gate MLP fused into phase1)
  k_phase1<<<NC_ * 32, 256, 0, stream>>>(pbuf, Wgk2, bgk, obuf, Ubuf, dbuf);
  k_phase2<<<(32 * 1024) / 256, 256, 0, stream>>>(Ubuf, dbuf, Sbuf);
  k_phase3rms<<<NC_ * 32, 256, 0, stream>>>(pbuf, obuf, Sbuf, nw, ybuf);

  // output projection (f32 out), XCD-swizzled
  k_gemm_bt<float><<<(D_/128) * (M_/128), 256, 0, stream>>>(ybuf, woT, out, M_, D_, VD_);
}

// Round 6
// 249.273 us; speedup vs baseline: 2.5839x; 1.2521x over previous
//
#include <hip/hip_runtime.h>
#include <cstddef>

#define B_   2
#define T_   4096
#define D_   1024
#define H_   16
#define KD_  512
#define VD_  1024
#define NC_  64          // T/CHUNK
#define M_   (B_*T_)     // 8192
#define GR_  16
#define EPS_ 1e-5f
#define SCALE_ 0.17677669529663687f  // 32^-0.5
#define GNORM_INV_ (1.0f/16.0f)

// fused projection layout: cols [0,512)=q, [512,1024)=k, [1024,2048)=v,
// [2048,3072)=g, [3072,3200)=glow (only first 16 weight rows nonzero)
#define NF_   3200
#define Q0_   0
#define K0_   512
#define V0_   1024
#define G0_   2048
#define GL0_  3072

typedef __attribute__((ext_vector_type(8))) __bf16 bf16x8;
typedef __attribute__((ext_vector_type(4))) float f32x4;

__device__ inline unsigned short f2bf(float f) {
  unsigned int u = __float_as_uint(f);
  u = (u + 0x7fffu + ((u >> 16) & 1u)) >> 16;
  return (unsigned short)u;
}
__device__ inline float bf2f(unsigned short u) {
  return __uint_as_float((unsigned int)u << 16);
}
__device__ inline void unpack8(uint4 u, float* f) {
  f[0] = bf2f(u.x & 0xffff); f[1] = bf2f(u.x >> 16);
  f[2] = bf2f(u.y & 0xffff); f[3] = bf2f(u.y >> 16);
  f[4] = bf2f(u.z & 0xffff); f[5] = bf2f(u.z >> 16);
  f[6] = bf2f(u.w & 0xffff); f[7] = bf2f(u.w >> 16);
}
__device__ inline uint4 pack8(const unsigned short* s) {
  uint4 u;
  u.x = (unsigned int)s[0] | ((unsigned int)s[1] << 16);
  u.y = (unsigned int)s[2] | ((unsigned int)s[3] << 16);
  u.z = (unsigned int)s[4] | ((unsigned int)s[5] << 16);
  u.w = (unsigned int)s[6] | ((unsigned int)s[7] << 16);
  return u;
}

__device__ __forceinline__ void gload_lds16(const unsigned short* g, unsigned short* l) {
  __builtin_amdgcn_global_load_lds(
      (const __attribute__((address_space(1))) unsigned int*)g,
      (__attribute__((address_space(3))) unsigned int*)l, 16, 0, 0);
}

// ---------------- elementwise conversions ----------------

__global__ __launch_bounds__(256) void k_f32_to_bf16(const float* __restrict__ in,
                                                     unsigned short* __restrict__ out, int n4) {
  int i = (blockIdx.x * 256 + threadIdx.x) * 4;
  float4 f = *(const float4*)(in + i);
  ushort4 o;
  o.x = f2bf(f.x); o.y = f2bf(f.y); o.z = f2bf(f.z); o.w = f2bf(f.w);
  *(ushort4*)(out + i) = o;
}

// all weight transposes (+Wgk1 pad) in one launch. z selects the matrix.
__global__ __launch_bounds__(256) void k_transpose_all(const float* __restrict__ Wq,
                                                       const float* __restrict__ Wk,
                                                       const float* __restrict__ Wv,
                                                       const float* __restrict__ Wg,
                                                       const float* __restrict__ Wo,
                                                       const float* __restrict__ Wgk1,
                                                       unsigned short* __restrict__ Wcat,
                                                       unsigned short* __restrict__ woT) {
  __shared__ float tile[32][33];
  const float* in; unsigned short* out; int N;
  switch (blockIdx.z) {
    case 0: in = Wq;   out = Wcat + (size_t)Q0_ * D_;  N = 512;  break;
    case 1: in = Wk;   out = Wcat + (size_t)K0_ * D_;  N = 512;  break;
    case 2: in = Wv;   out = Wcat + (size_t)V0_ * D_;  N = 1024; break;
    case 3: in = Wg;   out = Wcat + (size_t)G0_ * D_;  N = 1024; break;
    case 4: in = Wo;   out = woT;                      N = 1024; break;
    default: in = Wgk1; out = Wcat + (size_t)GL0_ * D_; N = 128;  break;  // pad: cols >= 16 are 0
  }
  int n0 = blockIdx.x * 32, k0 = blockIdx.y * 32;
  if (n0 >= N) return;
  int tx = threadIdx.x & 31, ty = threadIdx.x >> 5;   // 32 x 8
  if (blockIdx.z == 5) {
#pragma unroll
    for (int p = 0; p < 4; ++p)
      tile[ty + p*8][tx] = (n0 + tx < GR_) ? in[(size_t)(k0 + ty + p*8) * GR_ + n0 + tx] : 0.0f;
  } else {
#pragma unroll
    for (int p = 0; p < 4; ++p)
      tile[ty + p*8][tx] = in[(size_t)(k0 + ty + p*8) * N + n0 + tx];
  }
  __syncthreads();
#pragma unroll
  for (int p = 0; p < 4; ++p)
    out[(size_t)(n0 + ty + p*8) * 1024 + k0 + tx] = f2bf(tile[tx][ty + p*8]);
}

// ---------------- bf16 MFMA GEMM: C(MxN) = A(MxK) * Bt(NxK)^T ----------------
// 128x128 tile, BK=64, 256 threads (4 waves 2x2), 16x16x32 MFMA.
// XCD-aware 1D swizzle; global_load_lds width=16 with source-column XOR swizzle.

template <typename OutT>
__global__ __launch_bounds__(256) void k_gemm_bt(const unsigned short* __restrict__ A,
                                                 const unsigned short* __restrict__ Bt,
                                                 OutT* __restrict__ C,
                                                 int M, int N, int K) {
  __shared__ __align__(16) unsigned short sA[128 * 64];
  __shared__ __align__(16) unsigned short sB[128 * 64];
  const int tid  = threadIdx.x;
  const int lane = tid & 63;
  const int wave = tid >> 6;
  const int wr = wave >> 1, wc = wave & 1;
  const int quad = lane >> 4, l16 = lane & 15;

  const int g = blockIdx.x;
  const int xcd = g & 7, slot = g >> 3;
  const int bm0 = ((xcd << 3) | (slot & 7)) << 7;   // M-tile
  const int bn0 = (slot >> 3) << 7;                 // N-tile

  const int lrow = lane >> 3;                      // 0..7 (== row & 7)
  const int gcol = ((lane & 7) ^ lrow) * 8;        // swizzled source column
  const unsigned short* ga = A  + (size_t)(bm0 + wave * 8 + lrow) * K + gcol;
  const unsigned short* gb = Bt + (size_t)(bn0 + wave * 8 + lrow) * K + gcol;
  unsigned short* la = sA + wave * 8 * 64;
  unsigned short* lb = sB + wave * 8 * 64;

  f32x4 acc[4][4] = {};

  for (int k0 = 0; k0 < K; k0 += 64) {
#pragma unroll
    for (int it = 0; it < 4; ++it) {
      gload_lds16(ga + k0 + (size_t)it * 32 * K, la + it * 32 * 64);
      gload_lds16(gb + k0 + (size_t)it * 32 * K, lb + it * 32 * 64);
    }
    __syncthreads();
#pragma unroll
    for (int kk = 0; kk < 2; ++kk) {
      bf16x8 af[4], bfv[4];
#pragma unroll
      for (int i = 0; i < 4; ++i) {
        int row = wr * 64 + i * 16 + l16;
        int gg = (kk * 4 + quad) ^ (row & 7);
        af[i] = *(const bf16x8*)(sA + row * 64 + gg * 8);
      }
#pragma unroll
      for (int j = 0; j < 4; ++j) {
        int row = wc * 64 + j * 16 + l16;
        int gg = (kk * 4 + quad) ^ (row & 7);
        bfv[j] = *(const bf16x8*)(sB + row * 64 + gg * 8);
      }
#pragma unroll
      for (int i = 0; i < 4; ++i)
#pragma unroll
        for (int j = 0; j < 4; ++j)
          acc[i][j] = __builtin_amdgcn_mfma_f32_16x16x32_bf16(af[i], bfv[j], acc[i][j], 0, 0, 0);
    }
    __syncthreads();
  }

#pragma unroll
  for (int i = 0; i < 4; ++i) {
    int row0 = bm0 + wr * 64 + i * 16 + quad * 4;
#pragma unroll
    for (int j = 0; j < 4; ++j) {
      int col = bn0 + wc * 64 + j * 16 + l16;
#pragma unroll
      for (int r = 0; r < 4; ++r) {
        float v = acc[i][j][r];
        if constexpr (sizeof(OutT) == 2)
          C[(size_t)(row0 + r) * N + col] = (OutT)f2bf(v);
        else
          C[(size_t)(row0 + r) * N + col] = (OutT)v;
      }
    }
  }
}

// ---------------- phase 1 (MFMA): gate MLP + cumsum + intra-chunk attention ----------------
// One block per (chunk, b, h). All matmuls via mfma_f32_16x16x32_bf16.
// Operand LDS strides: K=32 ops -> 40 bf16/row, K=64 ops -> 72 bf16/row
// (stride*8lanes covers 8 distinct bank-quads -> conflict-free ds_read_b128).
// Outputs: qe -> pbuf (bf16), o_intra -> obuf (bf16 row-major per chunk-head),
// Ut (transposed: [vd][d], bf16), dvec (f32).

#define P1_SGLOW 0         // 64 x 16 bf16            (2048)
#define P1_SW2   2048      // 16 x 32 f32             (2048)
#define P1_SBGK  4096      // 32 f32 (+pad)           (128)
#define P1_QN    4224      // 64 x 40 bf16            (5120)
#define P1_KN    9344      // 64 x 40 bf16            (5120)
#define P1_VN    14464     // 64 x 72 bf16            (9216)
#define P1_VT    23680     // 64 x 72 bf16 (v^T)      (9216)
#define P1_QEA   32896     // 64 x 40 bf16 (qe)       (5120)
#define P1_KEB   38016     // 64 x 40 bf16 (ke2)      (5120)
#define P1_KET   43136     // 32 x 72 bf16 (ke2^T)    (4608)
#define P1_EBL   47744     // 32 f32                  (128)
#define P1_AL    P1_QN     // 64 x 72 bf16 overlay on q_n+k_n (9216 <= 10240)
#define P1_SIZE  47872

__global__ __launch_bounds__(256) void k_phase1(unsigned short* __restrict__ pbuf,
                                                const float* __restrict__ Wgk2,
                                                const float* __restrict__ bgk,
                                                unsigned short* __restrict__ obuf,
                                                unsigned short* __restrict__ Ut,
                                                float* __restrict__ dvec) {
  const int bi = blockIdx.x;
  const int c = bi >> 5, bh = bi & 31;
  const int b = bh >> 4, h = bh & 15;
  const int tid = threadIdx.x;
  const int lane = tid & 63, w = tid >> 6;
  const int quad = lane >> 4, l16 = lane & 15;

  __shared__ __align__(16) char sm[P1_SIZE];

  const size_t row0 = (size_t)(b * T_ + c * 64);
  const size_t rq  = row0 * NF_ + Q0_ + h * 32;
  const size_t rk  = row0 * NF_ + K0_ + h * 32;
  const size_t rv  = row0 * NF_ + V0_ + h * 64;
  const size_t rgl = row0 * NF_ + GL0_;
  const size_t cb  = (size_t)c * 32 + bh;

  // ---- staging (coalesced uint4) ----
  {
    int i = tid >> 2, seg = tid & 3;
    uint4 qu = *(const uint4*)(pbuf + rq + (size_t)i * NF_ + seg * 8);
    uint4 ku = *(const uint4*)(pbuf + rk + (size_t)i * NF_ + seg * 8);
    *(uint4*)(sm + P1_QN + i * 80 + seg * 16) = qu;
    *(uint4*)(sm + P1_KN + i * 80 + seg * 16) = ku;
  }
#pragma unroll
  for (int s = 0; s < 2; ++s) {
    int e = tid + s * 256;
    int j = e >> 3, seg = e & 7;
    uint4 vu = *(const uint4*)(pbuf + rv + (size_t)j * NF_ + seg * 8);
    *(uint4*)(sm + P1_VN + j * 144 + seg * 16) = vu;
  }
  if (tid < 128) {
    int i = tid >> 1, seg = tid & 1;
    uint4 gu = *(const uint4*)(pbuf + rgl + (size_t)i * NF_ + seg * 8);
    *(uint4*)(sm + P1_SGLOW + i * 32 + seg * 16) = gu;
    int r = tid >> 3, d4 = (tid & 7) * 4;
    *(float4*)(sm + P1_SW2 + (r * 32 + d4) * 4) = *(const float4*)(Wgk2 + r * KD_ + h * 32 + d4);
  }
  if (tid < 8)
    *(float4*)(sm + P1_SBGK + tid * 16) = *(const float4*)(bgk + h * 32 + tid * 4);
  __syncthreads();

  // ---- v transpose: v_n[j][vd] -> v_t[vd][j] ----
  {
    int vd = tid & 63, jg = tid >> 6;
#pragma unroll
    for (int half = 0; half < 2; ++half) {
      int j0 = jg * 8 + half * 32;
      unsigned short t8[8];
#pragma unroll
      for (int jj = 0; jj < 8; ++jj)
        t8[jj] = *(const unsigned short*)(sm + P1_VN + (j0 + jj) * 144 + vd * 2);
      *(uint4*)(sm + P1_VT + vd * 144 + j0 * 2) = pack8(t8);
    }
  }

  // ---- gate MLP + cumsum + qe/ke2 repack (thread: i=lane, 8 d's = wave*8..) ----
  {
    const int i = lane, dg = w;
    float gl[16];
    unpack8(*(const uint4*)(sm + P1_SGLOW + i * 32), gl);
    unpack8(*(const uint4*)(sm + P1_SGLOW + i * 32 + 16), gl + 8);
    float s[8];
    {
      float4 b0 = *(const float4*)(sm + P1_SBGK + dg * 32);
      float4 b1 = *(const float4*)(sm + P1_SBGK + dg * 32 + 16);
      s[0] = b0.x; s[1] = b0.y; s[2] = b0.z; s[3] = b0.w;
      s[4] = b1.x; s[5] = b1.y; s[6] = b1.z; s[7] = b1.w;
    }
#pragma unroll
    for (int r = 0; r < 16; ++r) {
      float4 wa = *(const float4*)(sm + P1_SW2 + (r * 32 + dg * 8) * 4);
      float4 wb = *(const float4*)(sm + P1_SW2 + (r * 32 + dg * 8) * 4 + 16);
      float gv = gl[r];
      s[0] += gv * wa.x; s[1] += gv * wa.y; s[2] += gv * wa.z; s[3] += gv * wa.w;
      s[4] += gv * wb.x; s[5] += gv * wb.y; s[6] += gv * wb.z; s[7] += gv * wb.w;
    }
    float bb[8];
#pragma unroll
    for (int j = 0; j < 8; ++j) {
      float ls = fminf(s[j], 0.0f) - __logf(1.0f + __expf(-fabsf(s[j])));
      float v = ls * GNORM_INV_;
#pragma unroll
      for (int off = 1; off < 64; off <<= 1) {
        int src = lane - off;
        float t2 = __shfl(v, src < 0 ? 0 : src, 64);
        if (lane >= off) v += t2;
      }
      bb[j] = v;
    }
    if (lane == 63) {
#pragma unroll
      for (int j = 0; j < 8; ++j) {
        float e = __expf(bb[j]);
        ((float*)(sm + P1_EBL))[dg * 8 + j] = e;
        dvec[cb * 32 + dg * 8 + j] = e;
      }
    }
    float qf[8], kf[8];
    unpack8(*(const uint4*)(sm + P1_QN + i * 80 + dg * 16), qf);
    unpack8(*(const uint4*)(sm + P1_KN + i * 80 + dg * 16), kf);
    unsigned short qo[8], ko[8];
#pragma unroll
    for (int j = 0; j < 8; ++j) {
      float eb = __expf(bb[j]);
      float ie = __expf(-bb[j]);
      qo[j] = f2bf(qf[j] * eb * SCALE_);
      ko[j] = f2bf(kf[j] * ie);
      *(unsigned short*)(sm + P1_KET + (dg * 8 + j) * 144 + i * 2) = ko[j];
    }
    *(uint4*)(sm + P1_QEA + i * 80 + dg * 16) = pack8(qo);
    *(uint4*)(sm + P1_KEB + i * 80 + dg * 16) = pack8(ko);
  }
  __syncthreads();

  // ---- qe writeback to pbuf (for phase 3) ----
  {
    int i = tid >> 2, seg = tid & 3;
    *(uint4*)(pbuf + rq + (size_t)i * NF_ + seg * 8) =
        *(const uint4*)(sm + P1_QEA + i * 80 + seg * 16);
  }

  // ---- QK^T: A_s = qe . ke2^T (4 MFMA/wave) ----
  const int tm = w;
  bf16x8 aq = *(const bf16x8*)(sm + P1_QEA + (tm * 16 + l16) * 80 + quad * 16);
  f32x4 cA[4] = {};
#pragma unroll
  for (int tn = 0; tn < 4; ++tn) {
    bf16x8 bk = *(const bf16x8*)(sm + P1_KEB + (tn * 16 + l16) * 80 + quad * 16);
    cA[tn] = __builtin_amdgcn_mfma_f32_16x16x32_bf16(aq, bk, cA[tn], 0, 0, 0);
  }

  // ---- U = ke2^T . v, scaled by exp(b_last) -> Ut[vd][d] (4 MFMA/wave) ----
  {
    const int um = w >> 1;
    bf16x8 ak0 = *(const bf16x8*)(sm + P1_KET + (um * 16 + l16) * 144 + quad * 16);
    bf16x8 ak1 = *(const bf16x8*)(sm + P1_KET + (um * 16 + l16) * 144 + quad * 16 + 64);
    f32x4 cU[2] = {};
#pragma unroll
    for (int e = 0; e < 2; ++e) {
      int un = (w & 1) * 2 + e;
      bf16x8 bv0 = *(const bf16x8*)(sm + P1_VT + (un * 16 + l16) * 144 + quad * 16);
      bf16x8 bv1 = *(const bf16x8*)(sm + P1_VT + (un * 16 + l16) * 144 + quad * 16 + 64);
      cU[e] = __builtin_amdgcn_mfma_f32_16x16x32_bf16(ak0, bv0, cU[e], 0, 0, 0);
      cU[e] = __builtin_amdgcn_mfma_f32_16x16x32_bf16(ak1, bv1, cU[e], 0, 0, 0);
    }
#pragma unroll
    for (int e = 0; e < 2; ++e) {
      int un = (w & 1) * 2 + e;
#pragma unroll
      for (int r = 0; r < 4; ++r) {
        int d = um * 16 + quad * 4 + r;
        int vd = un * 16 + l16;
        float eb = ((const float*)(sm + P1_EBL))[d];
        Ut[cb * 2048 + vd * 32 + d] = f2bf(cU[e][r] * eb);
      }
    }
  }

  // ---- mask A_s (tril) -> A_l bf16 (overlay on q_n/k_n: dead after repack) ----
#pragma unroll
  for (int tn = 0; tn < 4; ++tn)
#pragma unroll
    for (int r = 0; r < 4; ++r) {
      int row = tm * 16 + quad * 4 + r;
      int col = tn * 16 + l16;
      float av = (col <= row) ? cA[tn][r] : 0.0f;
      *(unsigned short*)(sm + P1_AL + row * 144 + col * 2) = f2bf(av);
    }
  __syncthreads();

  // ---- o_intra = A_s . v -> obuf (8 MFMA/wave) ----
  {
    bf16x8 aA0 = *(const bf16x8*)(sm + P1_AL + (tm * 16 + l16) * 144 + quad * 16);
    bf16x8 aA1 = *(const bf16x8*)(sm + P1_AL + (tm * 16 + l16) * 144 + quad * 16 + 64);
#pragma unroll
    for (int tn = 0; tn < 4; ++tn) {
      bf16x8 bv0 = *(const bf16x8*)(sm + P1_VT + (tn * 16 + l16) * 144 + quad * 16);
      bf16x8 bv1 = *(const bf16x8*)(sm + P1_VT + (tn * 16 + l16) * 144 + quad * 16 + 64);
      f32x4 co = {};
      co = __builtin_amdgcn_mfma_f32_16x16x32_bf16(aA0, bv0, co, 0, 0, 0);
      co = __builtin_amdgcn_mfma_f32_16x16x32_bf16(aA1, bv1, co, 0, 0, 0);
#pragma unroll
      for (int r = 0; r < 4; ++r) {
        int row = tm * 16 + quad * 4 + r;
        int col = tn * 16 + l16;
        obuf[cb * 4096 + row * 64 + col] = f2bf(co[r]);
      }
    }
  }
}

// ---------------- phase 2: inter-chunk state recurrence (coalesced on [vd][d]) ----------------

__global__ __launch_bounds__(256) void k_phase2(const unsigned short* __restrict__ Ut,
                                                const float* __restrict__ dvec,
                                                unsigned short* __restrict__ Sp) {
  int idx = blockIdx.x * 256 + threadIdx.x;   // 32768
  int bh = idx >> 10, q = idx & 1023;
  int vd = q >> 4, d2 = (q & 15) * 2;
  float run0 = 0.0f, run1 = 0.0f;
  for (int c = 0; c < NC_; ++c) {
    size_t o = ((size_t)c * 32 + bh) * 2048 + vd * 32 + d2;
    unsigned int uu = *(const unsigned int*)(Ut + o);
    *(unsigned int*)(Sp + o) =
        (unsigned int)f2bf(run0) | ((unsigned int)f2bf(run1) << 16);
    float dv0 = dvec[((size_t)c * 32 + bh) * 32 + d2];
    float dv1 = dvec[((size_t)c * 32 + bh) * 32 + d2 + 1];
    run0 = dv0 * run0 + bf2f(uu & 0xffff);
    run1 = dv1 * run1 + bf2f(uu >> 16);
  }
}

// ---------------- phase 3 (MFMA): o = o_intra + qe.S, fused RMS/swish -> ybuf ----------------

#define P3_QEA 0          // 64 x 40 bf16  (5120)
#define P3_SL  5120       // 64 x 40 bf16 (S rows vd, 32 d each) (5120)
#define P3_OL  10240      // 64 x 68 f32   (17408)
#define P3_SIZE 27648

__global__ __launch_bounds__(256) void k_phase3rms(const unsigned short* __restrict__ pbuf,
                                                   const unsigned short* __restrict__ obuf,
                                                   const unsigned short* __restrict__ Sp,
                                                   const float* __restrict__ norm_w,
                                                   unsigned short* __restrict__ ybuf) {
  const int bi = blockIdx.x;
  const int c = bi >> 5, bh = bi & 31;
  const int b = bh >> 4, h = bh & 15;
  const int tid = threadIdx.x;
  const int lane = tid & 63, w = tid >> 6;
  const int quad = lane >> 4, l16 = lane & 15;

  __shared__ __align__(16) char sm[P3_SIZE];

  const size_t row0 = (size_t)(b * T_ + c * 64);
  const size_t rq = row0 * NF_ + Q0_ + h * 32;
  const size_t cb = (size_t)c * 32 + bh;

  {
    int i = tid >> 2, seg = tid & 3;
    *(uint4*)(sm + P3_QEA + i * 80 + seg * 16) =
        *(const uint4*)(pbuf + rq + (size_t)i * NF_ + seg * 8);
    // S tile: all 256 threads, 4 segs x 16 B = full 32-d row per vd
    *(uint4*)(sm + P3_SL + i * 80 + seg * 16) =
        *(const uint4*)(Sp + cb * 2048 + (size_t)i * 32 + seg * 8);
  }
  __syncthreads();

  const int tm = w;
  bf16x8 aq = *(const bf16x8*)(sm + P3_QEA + (tm * 16 + l16) * 80 + quad * 16);
#pragma unroll
  for (int tn = 0; tn < 4; ++tn) {
    bf16x8 bs = *(const bf16x8*)(sm + P3_SL + (tn * 16 + l16) * 80 + quad * 16);
    f32x4 co = {};
    co = __builtin_amdgcn_mfma_f32_16x16x32_bf16(aq, bs, co, 0, 0, 0);
#pragma unroll
    for (int r = 0; r < 4; ++r) {
      int row = tm * 16 + quad * 4 + r;
      int col = tn * 16 + l16;
      float o = co[r] + bf2f(obuf[cb * 4096 + row * 64 + col]);
      *(float*)(sm + P3_OL + (row * 68 + col) * 4) = o;
    }
  }
  __syncthreads();

  // RMS + swish: thread = (2 rows, 8 vd each)
  {
    int r0 = tid >> 3, s8 = tid & 7;
#pragma unroll
    for (int half = 0; half < 2; ++half) {
      int row = r0 + half * 32;
      float4 a  = *(const float4*)(sm + P3_OL + (row * 68 + s8 * 8) * 4);
      float4 b4 = *(const float4*)(sm + P3_OL + (row * 68 + s8 * 8) * 4 + 16);
      float p = a.x*a.x + a.y*a.y + a.z*a.z + a.w*a.w
              + b4.x*b4.x + b4.y*b4.y + b4.z*b4.z + b4.w*b4.w;
      p += __shfl_xor(p, 1, 64);
      p += __shfl_xor(p, 2, 64);
      p += __shfl_xor(p, 4, 64);
      float rs = rsqrtf(p * (1.0f / 64.0f) + EPS_);
      size_t m = row0 + row;
      float gv[8];
      unpack8(*(const uint4*)(pbuf + m * NF_ + G0_ + h * 64 + s8 * 8), gv);
      float4 n0 = *(const float4*)(norm_w + s8 * 8);
      float4 n1 = *(const float4*)(norm_w + s8 * 8 + 4);
      float nw[8] = {n0.x, n0.y, n0.z, n0.w, n1.x, n1.y, n1.z, n1.w};
      float ov[8] = {a.x, a.y, a.z, a.w, b4.x, b4.y, b4.z, b4.w};
      unsigned short yo[8];
#pragma unroll
      for (int j = 0; j < 8; ++j) {
        float sw = gv[j] / (1.0f + __expf(-gv[j]));
        yo[j] = f2bf(ov[j] * rs * nw[j] * sw);
      }
      *(uint4*)(ybuf + m * VD_ + h * 64 + s8 * 8) = pack8(yo);
    }
  }
}

// ---------------- launch ----------------

extern "C" void kernel_launch(void* const* d_in, const int* in_sizes, int n_in,
                              void* d_out, int out_size, void* d_ws, size_t ws_size,
                              hipStream_t stream) {
  const float* x    = (const float*)d_in[0];
  const float* Wq   = (const float*)d_in[1];
  const float* Wk   = (const float*)d_in[2];
  const float* Wv   = (const float*)d_in[3];
  const float* Wgk1 = (const float*)d_in[4];
  const float* Wgk2 = (const float*)d_in[5];
  const float* bgk  = (const float*)d_in[6];
  const float* Wg   = (const float*)d_in[7];
  const float* nw   = (const float*)d_in[8];
  const float* Wo   = (const float*)d_in[9];
  float* out = (float*)d_out;

  char* p = (char*)d_ws;
  unsigned short* xb   = (unsigned short*)p;  p += (size_t)M_ * D_ * 2;
  unsigned short* Wcat = (unsigned short*)p;  p += (size_t)NF_ * D_ * 2;
  unsigned short* woT  = (unsigned short*)p;  p += (size_t)D_ * VD_ * 2;
  unsigned short* pbuf = (unsigned short*)p;  p += (size_t)M_ * NF_ * 2;
  unsigned short* obuf = (unsigned short*)p;  p += (size_t)M_ * VD_ * 2;
  unsigned short* Ubuf = (unsigned short*)p;  p += (size_t)NC_ * 32 * 2048 * 2;
  unsigned short* Sbuf = (unsigned short*)p;  p += (size_t)NC_ * 32 * 2048 * 2;
  float* dbuf = (float*)p;                    p += (size_t)NC_ * 32 * 32 * 4;
  unsigned short* ybuf = (unsigned short*)p;  p += (size_t)M_ * VD_ * 2;

  // conversions
  k_f32_to_bf16<<<(M_ * D_ / 4) / 256, 256, 0, stream>>>(x, xb, M_ * D_);
  k_transpose_all<<<dim3(32, 32, 6), 256, 0, stream>>>(Wq, Wk, Wv, Wg, Wo, Wgk1, Wcat, woT);

  // fused projections: q|k|v|g|glow in one GEMM (bf16 out), XCD-swizzled
  k_gemm_bt<unsigned short><<<(NF_/128) * (M_/128), 256, 0, stream>>>(xb, Wcat, pbuf, M_, NF_, D_);

  // attention (all matmuls MFMA)
  k_phase1<<<NC_ * 32, 256, 0, stream>>>(pbuf, Wgk2, bgk, obuf, Ubuf, dbuf);
  k_phase2<<<128, 256, 0, stream>>>(Ubuf, dbuf, Sbuf);
  k_phase3rms<<<NC_ * 32, 256, 0, stream>>>(pbuf, obuf, Sbuf, nw, ybuf);

  // output projection (f32 out), XCD-swizzled
  k_gemm_bt<float><<<(D_/128) * (M_/128), 256, 0, stream>>>(ybuf, woT, out, M_, D_, VD_);
}

// Round 7
// 230.905 us; speedup vs baseline: 2.7894x; 1.0795x over previous
//
#include <hip/hip_runtime.h>
#include <cstddef>

#define B_   2
#define T_   4096
#define D_   1024
#define H_   16
#define KD_  512
#define VD_  1024
#define NC_  64          // T/CHUNK
#define M_   (B_*T_)     // 8192
#define GR_  16
#define EPS_ 1e-5f
#define SCALE_ 0.17677669529663687f  // 32^-0.5
#define GNORM_INV_ (1.0f/16.0f)

// fused projection layout: cols [0,512)=q, [512,1024)=k, [1024,2048)=v,
// [2048,3072)=g, [3072,3200)=glow (only first 16 weight rows nonzero)
#define NF_   3200
#define Q0_   0
#define K0_   512
#define V0_   1024
#define G0_   2048
#define GL0_  3072

typedef __attribute__((ext_vector_type(8))) __bf16 bf16x8;
typedef __attribute__((ext_vector_type(4))) float f32x4;

__device__ inline unsigned short f2bf(float f) {
  unsigned int u = __float_as_uint(f);
  u = (u + 0x7fffu + ((u >> 16) & 1u)) >> 16;
  return (unsigned short)u;
}
__device__ inline float bf2f(unsigned short u) {
  return __uint_as_float((unsigned int)u << 16);
}
__device__ inline void unpack8(uint4 u, float* f) {
  f[0] = bf2f(u.x & 0xffff); f[1] = bf2f(u.x >> 16);
  f[2] = bf2f(u.y & 0xffff); f[3] = bf2f(u.y >> 16);
  f[4] = bf2f(u.z & 0xffff); f[5] = bf2f(u.z >> 16);
  f[6] = bf2f(u.w & 0xffff); f[7] = bf2f(u.w >> 16);
}
__device__ inline uint4 pack8(const unsigned short* s) {
  uint4 u;
  u.x = (unsigned int)s[0] | ((unsigned int)s[1] << 16);
  u.y = (unsigned int)s[2] | ((unsigned int)s[3] << 16);
  u.z = (unsigned int)s[4] | ((unsigned int)s[5] << 16);
  u.w = (unsigned int)s[6] | ((unsigned int)s[7] << 16);
  return u;
}

__device__ __forceinline__ void gload_lds16(const unsigned short* g, unsigned short* l) {
  __builtin_amdgcn_global_load_lds(
      (const __attribute__((address_space(1))) unsigned int*)g,
      (__attribute__((address_space(3))) unsigned int*)l, 16, 0, 0);
}

// ---------------- elementwise conversions ----------------

__global__ __launch_bounds__(256) void k_f32_to_bf16(const float* __restrict__ in,
                                                     unsigned short* __restrict__ out, int n4) {
  int i = (blockIdx.x * 256 + threadIdx.x) * 4;
  float4 f = *(const float4*)(in + i);
  ushort4 o;
  o.x = f2bf(f.x); o.y = f2bf(f.y); o.z = f2bf(f.z); o.w = f2bf(f.w);
  *(ushort4*)(out + i) = o;
}

// all weight transposes (+Wgk1 pad) in one launch. z selects the matrix.
__global__ __launch_bounds__(256) void k_transpose_all(const float* __restrict__ Wq,
                                                       const float* __restrict__ Wk,
                                                       const float* __restrict__ Wv,
                                                       const float* __restrict__ Wg,
                                                       const float* __restrict__ Wo,
                                                       const float* __restrict__ Wgk1,
                                                       unsigned short* __restrict__ Wcat,
                                                       unsigned short* __restrict__ woT) {
  __shared__ float tile[32][33];
  const float* in; unsigned short* out; int N;
  switch (blockIdx.z) {
    case 0: in = Wq;   out = Wcat + (size_t)Q0_ * D_;  N = 512;  break;
    case 1: in = Wk;   out = Wcat + (size_t)K0_ * D_;  N = 512;  break;
    case 2: in = Wv;   out = Wcat + (size_t)V0_ * D_;  N = 1024; break;
    case 3: in = Wg;   out = Wcat + (size_t)G0_ * D_;  N = 1024; break;
    case 4: in = Wo;   out = woT;                      N = 1024; break;
    default: in = Wgk1; out = Wcat + (size_t)GL0_ * D_; N = 128;  break;  // pad: cols >= 16 are 0
  }
  int n0 = blockIdx.x * 32, k0 = blockIdx.y * 32;
  if (n0 >= N) return;
  int tx = threadIdx.x & 31, ty = threadIdx.x >> 5;   // 32 x 8
  if (blockIdx.z == 5) {
#pragma unroll
    for (int p = 0; p < 4; ++p)
      tile[ty + p*8][tx] = (n0 + tx < GR_) ? in[(size_t)(k0 + ty + p*8) * GR_ + n0 + tx] : 0.0f;
  } else {
#pragma unroll
    for (int p = 0; p < 4; ++p)
      tile[ty + p*8][tx] = in[(size_t)(k0 + ty + p*8) * N + n0 + tx];
  }
  __syncthreads();
#pragma unroll
  for (int p = 0; p < 4; ++p)
    out[(size_t)(n0 + ty + p*8) * 1024 + k0 + tx] = f2bf(tile[tx][ty + p*8]);
}

// ---------------- bf16 MFMA GEMM: C(MxN) = A(MxK) * Bt(NxK)^T ----------------
// 128x128 tile, BK=64, 256 threads (4 waves 2x2), 16x16x32 MFMA.
// XCD-aware 1D swizzle; global_load_lds width=16 with source-column XOR swizzle.
// __launch_bounds__(256,3): request 3 blocks/CU (VGPR 80 + AGPR 64 = 144/wave
// fits the 170/wave cap at 3 waves/EU; LDS 32 KB allows 5).

template <typename OutT>
__global__ __launch_bounds__(256, 3) void k_gemm_bt(const unsigned short* __restrict__ A,
                                                    const unsigned short* __restrict__ Bt,
                                                    OutT* __restrict__ C,
                                                    int M, int N, int K) {
  __shared__ __align__(16) unsigned short sA[128 * 64];
  __shared__ __align__(16) unsigned short sB[128 * 64];
  const int tid  = threadIdx.x;
  const int lane = tid & 63;
  const int wave = tid >> 6;
  const int wr = wave >> 1, wc = wave & 1;
  const int quad = lane >> 4, l16 = lane & 15;

  const int g = blockIdx.x;
  const int xcd = g & 7, slot = g >> 3;
  const int bm0 = ((xcd << 3) | (slot & 7)) << 7;   // M-tile
  const int bn0 = (slot >> 3) << 7;                 // N-tile

  const int lrow = lane >> 3;                      // 0..7 (== row & 7)
  const int gcol = ((lane & 7) ^ lrow) * 8;        // swizzled source column
  const unsigned short* ga = A  + (size_t)(bm0 + wave * 8 + lrow) * K + gcol;
  const unsigned short* gb = Bt + (size_t)(bn0 + wave * 8 + lrow) * K + gcol;
  unsigned short* la = sA + wave * 8 * 64;
  unsigned short* lb = sB + wave * 8 * 64;

  f32x4 acc[4][4] = {};

  for (int k0 = 0; k0 < K; k0 += 64) {
#pragma unroll
    for (int it = 0; it < 4; ++it) {
      gload_lds16(ga + k0 + (size_t)it * 32 * K, la + it * 32 * 64);
      gload_lds16(gb + k0 + (size_t)it * 32 * K, lb + it * 32 * 64);
    }
    __syncthreads();
#pragma unroll
    for (int kk = 0; kk < 2; ++kk) {
      bf16x8 af[4], bfv[4];
#pragma unroll
      for (int i = 0; i < 4; ++i) {
        int row = wr * 64 + i * 16 + l16;
        int gg = (kk * 4 + quad) ^ (row & 7);
        af[i] = *(const bf16x8*)(sA + row * 64 + gg * 8);
      }
#pragma unroll
      for (int j = 0; j < 4; ++j) {
        int row = wc * 64 + j * 16 + l16;
        int gg = (kk * 4 + quad) ^ (row & 7);
        bfv[j] = *(const bf16x8*)(sB + row * 64 + gg * 8);
      }
#pragma unroll
      for (int i = 0; i < 4; ++i)
#pragma unroll
        for (int j = 0; j < 4; ++j)
          acc[i][j] = __builtin_amdgcn_mfma_f32_16x16x32_bf16(af[i], bfv[j], acc[i][j], 0, 0, 0);
    }
    __syncthreads();
  }

#pragma unroll
  for (int i = 0; i < 4; ++i) {
    int row0 = bm0 + wr * 64 + i * 16 + quad * 4;
#pragma unroll
    for (int j = 0; j < 4; ++j) {
      int col = bn0 + wc * 64 + j * 16 + l16;
#pragma unroll
      for (int r = 0; r < 4; ++r) {
        float v = acc[i][j][r];
        if constexpr (sizeof(OutT) == 2)
          C[(size_t)(row0 + r) * N + col] = (OutT)f2bf(v);
        else
          C[(size_t)(row0 + r) * N + col] = (OutT)v;
      }
    }
  }
}

// ---------------- phase 1 (MFMA): gate MLP + cumsum + intra-chunk attention ----------------
// One block per (chunk, b, h). All matmuls via mfma_f32_16x16x32_bf16.
// Operand LDS strides: K=32 ops -> 40 bf16/row, K=64 ops -> 72 bf16/row
// (stride*8lanes covers 8 distinct bank-quads -> conflict-free ds_read_b128).
// Outputs: qe -> pbuf (bf16), o_intra -> obuf (bf16 row-major per chunk-head),
// Ut (transposed: [vd][d], bf16), dvec (f32).

#define P1_SGLOW 0         // 64 x 16 bf16            (2048)
#define P1_SW2   2048      // 16 x 32 f32             (2048)
#define P1_SBGK  4096      // 32 f32 (+pad)           (128)
#define P1_QN    4224      // 64 x 40 bf16            (5120)
#define P1_KN    9344      // 64 x 40 bf16            (5120)
#define P1_VN    14464     // 64 x 72 bf16            (9216)
#define P1_VT    23680     // 64 x 72 bf16 (v^T)      (9216)
#define P1_QEA   32896     // 64 x 40 bf16 (qe)       (5120)
#define P1_KEB   38016     // 64 x 40 bf16 (ke2)      (5120)
#define P1_KET   43136     // 32 x 72 bf16 (ke2^T)    (4608)
#define P1_EBL   47744     // 32 f32                  (128)
#define P1_AL    P1_QN     // 64 x 72 bf16 overlay on q_n+k_n (9216 <= 10240)
#define P1_SIZE  47872

__global__ __launch_bounds__(256) void k_phase1(unsigned short* __restrict__ pbuf,
                                                const float* __restrict__ Wgk2,
                                                const float* __restrict__ bgk,
                                                unsigned short* __restrict__ obuf,
                                                unsigned short* __restrict__ Ut,
                                                float* __restrict__ dvec) {
  const int bi = blockIdx.x;
  const int c = bi >> 5, bh = bi & 31;
  const int b = bh >> 4, h = bh & 15;
  const int tid = threadIdx.x;
  const int lane = tid & 63, w = tid >> 6;
  const int quad = lane >> 4, l16 = lane & 15;

  __shared__ __align__(16) char sm[P1_SIZE];

  const size_t row0 = (size_t)(b * T_ + c * 64);
  const size_t rq  = row0 * NF_ + Q0_ + h * 32;
  const size_t rk  = row0 * NF_ + K0_ + h * 32;
  const size_t rv  = row0 * NF_ + V0_ + h * 64;
  const size_t rgl = row0 * NF_ + GL0_;
  const size_t cb  = (size_t)c * 32 + bh;

  // ---- staging (coalesced uint4) ----
  {
    int i = tid >> 2, seg = tid & 3;
    uint4 qu = *(const uint4*)(pbuf + rq + (size_t)i * NF_ + seg * 8);
    uint4 ku = *(const uint4*)(pbuf + rk + (size_t)i * NF_ + seg * 8);
    *(uint4*)(sm + P1_QN + i * 80 + seg * 16) = qu;
    *(uint4*)(sm + P1_KN + i * 80 + seg * 16) = ku;
  }
#pragma unroll
  for (int s = 0; s < 2; ++s) {
    int e = tid + s * 256;
    int j = e >> 3, seg = e & 7;
    uint4 vu = *(const uint4*)(pbuf + rv + (size_t)j * NF_ + seg * 8);
    *(uint4*)(sm + P1_VN + j * 144 + seg * 16) = vu;
  }
  if (tid < 128) {
    int i = tid >> 1, seg = tid & 1;
    uint4 gu = *(const uint4*)(pbuf + rgl + (size_t)i * NF_ + seg * 8);
    *(uint4*)(sm + P1_SGLOW + i * 32 + seg * 16) = gu;
    int r = tid >> 3, d4 = (tid & 7) * 4;
    *(float4*)(sm + P1_SW2 + (r * 32 + d4) * 4) = *(const float4*)(Wgk2 + r * KD_ + h * 32 + d4);
  }
  if (tid < 8)
    *(float4*)(sm + P1_SBGK + tid * 16) = *(const float4*)(bgk + h * 32 + tid * 4);
  __syncthreads();

  // ---- v transpose: v_n[j][vd] -> v_t[vd][j] ----
  {
    int vd = tid & 63, jg = tid >> 6;
#pragma unroll
    for (int half = 0; half < 2; ++half) {
      int j0 = jg * 8 + half * 32;
      unsigned short t8[8];
#pragma unroll
      for (int jj = 0; jj < 8; ++jj)
        t8[jj] = *(const unsigned short*)(sm + P1_VN + (j0 + jj) * 144 + vd * 2);
      *(uint4*)(sm + P1_VT + vd * 144 + j0 * 2) = pack8(t8);
    }
  }

  // ---- gate MLP + cumsum + qe/ke2 repack (thread: i=lane, 8 d's = wave*8..) ----
  {
    const int i = lane, dg = w;
    float gl[16];
    unpack8(*(const uint4*)(sm + P1_SGLOW + i * 32), gl);
    unpack8(*(const uint4*)(sm + P1_SGLOW + i * 32 + 16), gl + 8);
    float s[8];
    {
      float4 b0 = *(const float4*)(sm + P1_SBGK + dg * 32);
      float4 b1 = *(const float4*)(sm + P1_SBGK + dg * 32 + 16);
      s[0] = b0.x; s[1] = b0.y; s[2] = b0.z; s[3] = b0.w;
      s[4] = b1.x; s[5] = b1.y; s[6] = b1.z; s[7] = b1.w;
    }
#pragma unroll
    for (int r = 0; r < 16; ++r) {
      float4 wa = *(const float4*)(sm + P1_SW2 + (r * 32 + dg * 8) * 4);
      float4 wb = *(const float4*)(sm + P1_SW2 + (r * 32 + dg * 8) * 4 + 16);
      float gv = gl[r];
      s[0] += gv * wa.x; s[1] += gv * wa.y; s[2] += gv * wa.z; s[3] += gv * wa.w;
      s[4] += gv * wb.x; s[5] += gv * wb.y; s[6] += gv * wb.z; s[7] += gv * wb.w;
    }
    float bb[8];
#pragma unroll
    for (int j = 0; j < 8; ++j) {
      float ls = fminf(s[j], 0.0f) - __logf(1.0f + __expf(-fabsf(s[j])));
      float v = ls * GNORM_INV_;
#pragma unroll
      for (int off = 1; off < 64; off <<= 1) {
        int src = lane - off;
        float t2 = __shfl(v, src < 0 ? 0 : src, 64);
        if (lane >= off) v += t2;
      }
      bb[j] = v;
    }
    if (lane == 63) {
#pragma unroll
      for (int j = 0; j < 8; ++j) {
        float e = __expf(bb[j]);
        ((float*)(sm + P1_EBL))[dg * 8 + j] = e;
        dvec[cb * 32 + dg * 8 + j] = e;
      }
    }
    float qf[8], kf[8];
    unpack8(*(const uint4*)(sm + P1_QN + i * 80 + dg * 16), qf);
    unpack8(*(const uint4*)(sm + P1_KN + i * 80 + dg * 16), kf);
    unsigned short qo[8], ko[8];
#pragma unroll
    for (int j = 0; j < 8; ++j) {
      float eb = __expf(bb[j]);
      float ie = __expf(-bb[j]);
      qo[j] = f2bf(qf[j] * eb * SCALE_);
      ko[j] = f2bf(kf[j] * ie);
      *(unsigned short*)(sm + P1_KET + (dg * 8 + j) * 144 + i * 2) = ko[j];
    }
    *(uint4*)(sm + P1_QEA + i * 80 + dg * 16) = pack8(qo);
    *(uint4*)(sm + P1_KEB + i * 80 + dg * 16) = pack8(ko);
  }
  __syncthreads();

  // ---- qe writeback to pbuf (for phase 3) ----
  {
    int i = tid >> 2, seg = tid & 3;
    *(uint4*)(pbuf + rq + (size_t)i * NF_ + seg * 8) =
        *(const uint4*)(sm + P1_QEA + i * 80 + seg * 16);
  }

  // ---- QK^T: A_s = qe . ke2^T (4 MFMA/wave) ----
  const int tm = w;
  bf16x8 aq = *(const bf16x8*)(sm + P1_QEA + (tm * 16 + l16) * 80 + quad * 16);
  f32x4 cA[4] = {};
#pragma unroll
  for (int tn = 0; tn < 4; ++tn) {
    bf16x8 bk = *(const bf16x8*)(sm + P1_KEB + (tn * 16 + l16) * 80 + quad * 16);
    cA[tn] = __builtin_amdgcn_mfma_f32_16x16x32_bf16(aq, bk, cA[tn], 0, 0, 0);
  }

  // ---- U = ke2^T . v, scaled by exp(b_last) -> Ut[vd][d] (4 MFMA/wave) ----
  {
    const int um = w >> 1;
    bf16x8 ak0 = *(const bf16x8*)(sm + P1_KET + (um * 16 + l16) * 144 + quad * 16);
    bf16x8 ak1 = *(const bf16x8*)(sm + P1_KET + (um * 16 + l16) * 144 + quad * 16 + 64);
    f32x4 cU[2] = {};
#pragma unroll
    for (int e = 0; e < 2; ++e) {
      int un = (w & 1) * 2 + e;
      bf16x8 bv0 = *(const bf16x8*)(sm + P1_VT + (un * 16 + l16) * 144 + quad * 16);
      bf16x8 bv1 = *(const bf16x8*)(sm + P1_VT + (un * 16 + l16) * 144 + quad * 16 + 64);
      cU[e] = __builtin_amdgcn_mfma_f32_16x16x32_bf16(ak0, bv0, cU[e], 0, 0, 0);
      cU[e] = __builtin_amdgcn_mfma_f32_16x16x32_bf16(ak1, bv1, cU[e], 0, 0, 0);
    }
#pragma unroll
    for (int e = 0; e < 2; ++e) {
      int un = (w & 1) * 2 + e;
#pragma unroll
      for (int r = 0; r < 4; ++r) {
        int d = um * 16 + quad * 4 + r;
        int vd = un * 16 + l16;
        float eb = ((const float*)(sm + P1_EBL))[d];
        Ut[cb * 2048 + vd * 32 + d] = f2bf(cU[e][r] * eb);
      }
    }
  }

  // ---- mask A_s (tril) -> A_l bf16 (overlay on q_n/k_n: dead after repack) ----
#pragma unroll
  for (int tn = 0; tn < 4; ++tn)
#pragma unroll
    for (int r = 0; r < 4; ++r) {
      int row = tm * 16 + quad * 4 + r;
      int col = tn * 16 + l16;
      float av = (col <= row) ? cA[tn][r] : 0.0f;
      *(unsigned short*)(sm + P1_AL + row * 144 + col * 2) = f2bf(av);
    }
  __syncthreads();

  // ---- o_intra = A_s . v -> obuf (8 MFMA/wave) ----
  {
    bf16x8 aA0 = *(const bf16x8*)(sm + P1_AL + (tm * 16 + l16) * 144 + quad * 16);
    bf16x8 aA1 = *(const bf16x8*)(sm + P1_AL + (tm * 16 + l16) * 144 + quad * 16 + 64);
#pragma unroll
    for (int tn = 0; tn < 4; ++tn) {
      bf16x8 bv0 = *(const bf16x8*)(sm + P1_VT + (tn * 16 + l16) * 144 + quad * 16);
      bf16x8 bv1 = *(const bf16x8*)(sm + P1_VT + (tn * 16 + l16) * 144 + quad * 16 + 64);
      f32x4 co = {};
      co = __builtin_amdgcn_mfma_f32_16x16x32_bf16(aA0, bv0, co, 0, 0, 0);
      co = __builtin_amdgcn_mfma_f32_16x16x32_bf16(aA1, bv1, co, 0, 0, 0);
#pragma unroll
      for (int r = 0; r < 4; ++r) {
        int row = tm * 16 + quad * 4 + r;
        int col = tn * 16 + l16;
        obuf[cb * 4096 + row * 64 + col] = f2bf(co[r]);
      }
    }
  }
}

// ---------------- phase 2: inter-chunk state recurrence (coalesced on [vd][d]) ----------------
// 256 blocks x 128 threads: full-chip spread (was 128 blocks -> half the CUs idle).

__global__ __launch_bounds__(128) void k_phase2(const unsigned short* __restrict__ Ut,
                                                const float* __restrict__ dvec,
                                                unsigned short* __restrict__ Sp) {
  int idx = blockIdx.x * 128 + threadIdx.x;   // 32768
  int bh = idx >> 10, q = idx & 1023;
  int vd = q >> 4, d2 = (q & 15) * 2;
  float run0 = 0.0f, run1 = 0.0f;
  for (int c = 0; c < NC_; ++c) {
    size_t o = ((size_t)c * 32 + bh) * 2048 + vd * 32 + d2;
    unsigned int uu = *(const unsigned int*)(Ut + o);
    *(unsigned int*)(Sp + o) =
        (unsigned int)f2bf(run0) | ((unsigned int)f2bf(run1) << 16);
    float dv0 = dvec[((size_t)c * 32 + bh) * 32 + d2];
    float dv1 = dvec[((size_t)c * 32 + bh) * 32 + d2 + 1];
    run0 = dv0 * run0 + bf2f(uu & 0xffff);
    run1 = dv1 * run1 + bf2f(uu >> 16);
  }
}

// ---------------- phase 3 (MFMA): o = o_intra + qe.S, fused RMS/swish -> ybuf ----------------

#define P3_QEA 0          // 64 x 40 bf16  (5120)
#define P3_SL  5120       // 64 x 40 bf16 (S rows vd, 32 d each) (5120)
#define P3_OL  10240      // 64 x 68 f32   (17408)
#define P3_SIZE 27648

__global__ __launch_bounds__(256) void k_phase3rms(const unsigned short* __restrict__ pbuf,
                                                   const unsigned short* __restrict__ obuf,
                                                   const unsigned short* __restrict__ Sp,
                                                   const float* __restrict__ norm_w,
                                                   unsigned short* __restrict__ ybuf) {
  const int bi = blockIdx.x;
  const int c = bi >> 5, bh = bi & 31;
  const int b = bh >> 4, h = bh & 15;
  const int tid = threadIdx.x;
  const int lane = tid & 63, w = tid >> 6;
  const int quad = lane >> 4, l16 = lane & 15;

  __shared__ __align__(16) char sm[P3_SIZE];

  const size_t row0 = (size_t)(b * T_ + c * 64);
  const size_t rq = row0 * NF_ + Q0_ + h * 32;
  const size_t cb = (size_t)c * 32 + bh;

  {
    int i = tid >> 2, seg = tid & 3;
    *(uint4*)(sm + P3_QEA + i * 80 + seg * 16) =
        *(const uint4*)(pbuf + rq + (size_t)i * NF_ + seg * 8);
    // S tile: all 256 threads, 4 segs x 16 B = full 32-d row per vd
    *(uint4*)(sm + P3_SL + i * 80 + seg * 16) =
        *(const uint4*)(Sp + cb * 2048 + (size_t)i * 32 + seg * 8);
  }
  __syncthreads();

  const int tm = w;
  bf16x8 aq = *(const bf16x8*)(sm + P3_QEA + (tm * 16 + l16) * 80 + quad * 16);
#pragma unroll
  for (int tn = 0; tn < 4; ++tn) {
    bf16x8 bs = *(const bf16x8*)(sm + P3_SL + (tn * 16 + l16) * 80 + quad * 16);
    f32x4 co = {};
    co = __builtin_amdgcn_mfma_f32_16x16x32_bf16(aq, bs, co, 0, 0, 0);
#pragma unroll
    for (int r = 0; r < 4; ++r) {
      int row = tm * 16 + quad * 4 + r;
      int col = tn * 16 + l16;
      float o = co[r] + bf2f(obuf[cb * 4096 + row * 64 + col]);
      *(float*)(sm + P3_OL + (row * 68 + col) * 4) = o;
    }
  }
  __syncthreads();

  // RMS + swish: thread = (2 rows, 8 vd each)
  {
    int r0 = tid >> 3, s8 = tid & 7;
#pragma unroll
    for (int half = 0; half < 2; ++half) {
      int row = r0 + half * 32;
      float4 a  = *(const float4*)(sm + P3_OL + (row * 68 + s8 * 8) * 4);
      float4 b4 = *(const float4*)(sm + P3_OL + (row * 68 + s8 * 8) * 4 + 16);
      float p = a.x*a.x + a.y*a.y + a.z*a.z + a.w*a.w
              + b4.x*b4.x + b4.y*b4.y + b4.z*b4.z + b4.w*b4.w;
      p += __shfl_xor(p, 1, 64);
      p += __shfl_xor(p, 2, 64);
      p += __shfl_xor(p, 4, 64);
      float rs = rsqrtf(p * (1.0f / 64.0f) + EPS_);
      size_t m = row0 + row;
      float gv[8];
      unpack8(*(const uint4*)(pbuf + m * NF_ + G0_ + h * 64 + s8 * 8), gv);
      float4 n0 = *(const float4*)(norm_w + s8 * 8);
      float4 n1 = *(const float4*)(norm_w + s8 * 8 + 4);
      float nw[8] = {n0.x, n0.y, n0.z, n0.w, n1.x, n1.y, n1.z, n1.w};
      float ov[8] = {a.x, a.y, a.z, a.w, b4.x, b4.y, b4.z, b4.w};
      unsigned short yo[8];
#pragma unroll
      for (int j = 0; j < 8; ++j) {
        float sw = gv[j] / (1.0f + __expf(-gv[j]));
        yo[j] = f2bf(ov[j] * rs * nw[j] * sw);
      }
      *(uint4*)(ybuf + m * VD_ + h * 64 + s8 * 8) = pack8(yo);
    }
  }
}

// ---------------- launch ----------------

extern "C" void kernel_launch(void* const* d_in, const int* in_sizes, int n_in,
                              void* d_out, int out_size, void* d_ws, size_t ws_size,
                              hipStream_t stream) {
  const float* x    = (const float*)d_in[0];
  const float* Wq   = (const float*)d_in[1];
  const float* Wk   = (const float*)d_in[2];
  const float* Wv   = (const float*)d_in[3];
  const float* Wgk1 = (const float*)d_in[4];
  const float* Wgk2 = (const float*)d_in[5];
  const float* bgk  = (const float*)d_in[6];
  const float* Wg   = (const float*)d_in[7];
  const float* nw   = (const float*)d_in[8];
  const float* Wo   = (const float*)d_in[9];
  float* out = (float*)d_out;

  char* p = (char*)d_ws;
  unsigned short* xb   = (unsigned short*)p;  p += (size_t)M_ * D_ * 2;
  unsigned short* Wcat = (unsigned short*)p;  p += (size_t)NF_ * D_ * 2;
  unsigned short* woT  = (unsigned short*)p;  p += (size_t)D_ * VD_ * 2;
  unsigned short* pbuf = (unsigned short*)p;  p += (size_t)M_ * NF_ * 2;
  unsigned short* obuf = (unsigned short*)p;  p += (size_t)M_ * VD_ * 2;
  unsigned short* Ubuf = (unsigned short*)p;  p += (size_t)NC_ * 32 * 2048 * 2;
  unsigned short* Sbuf = (unsigned short*)p;  p += (size_t)NC_ * 32 * 2048 * 2;
  float* dbuf = (float*)p;                    p += (size_t)NC_ * 32 * 32 * 4;
  unsigned short* ybuf = (unsigned short*)p;  p += (size_t)M_ * VD_ * 2;

  // conversions
  k_f32_to_bf16<<<(M_ * D_ / 4) / 256, 256, 0, stream>>>(x, xb, M_ * D_);
  k_transpose_all<<<dim3(32, 32, 6), 256, 0, stream>>>(Wq, Wk, Wv, Wg, Wo, Wgk1, Wcat, woT);

  // fused projections: q|k|v|g|glow in one GEMM (bf16 out), XCD-swizzled
  k_gemm_bt<unsigned short><<<(NF_/128) * (M_/128), 256, 0, stream>>>(xb, Wcat, pbuf, M_, NF_, D_);

  // attention (all matmuls MFMA)
  k_phase1<<<NC_ * 32, 256, 0, stream>>>(pbuf, Wgk2, bgk, obuf, Ubuf, dbuf);
  k_phase2<<<256, 128, 0, stream>>>(Ubuf, dbuf, Sbuf);
  k_phase3rms<<<NC_ * 32, 256, 0, stream>>>(pbuf, obuf, Sbuf, nw, ybuf);

  // output projection (f32 out), XCD-swizzled
  k_gemm_bt<float><<<(D_/128) * (M_/128), 256, 0, stream>>>(ybuf, woT, out, M_, D_, VD_);
}